// Round 2
// baseline (411.546 us; speedup 1.0000x reference)
//
#include <hip/hip_runtime.h>
#include <hip/hip_bf16.h>

// B=8, C=512, N=2048, P=256.
// Round 12: LDS-bandwidth round for fused_attn (R1 showed ~66% of cycles are
// LDS traffic+conflicts; occupancy 20%, MfmaUtil 26):
//   - LDS cut 54.3KB -> 37.9KB: phi staged in 32-c chunks (FSTR 72->40),
//     G staged in 32-key chunks (GSTR 72->40), still aliased -> 4 blocks/CU.
//   - key-split kh 2->4 (grid 1024, 512 keys/block) to feed 4 blocks/CU.
//   - attn_merge now 4-way; ml state in dead xtL region; yp[4] fills fbf.
//   - __launch_bounds__(256,4) pins VGPR<=128 (R1 measured exactly 128 with
//     MORE staging regs, so this fits without spill).
// Predicted: Occupancy 20->38%, MfmaUtil 26->36, fused_attn 110->~75us.

typedef __attribute__((ext_vector_type(8))) short short8;
typedef __attribute__((ext_vector_type(4))) float floatx4;

// ---------------- bf16 helpers ----------------
__device__ __forceinline__ unsigned short f2bf(float v) {
    __hip_bfloat16 h = __float2bfloat16(v);
    return *(unsigned short*)&h;
}
__device__ __forceinline__ float bf2f(unsigned short u) {
    __hip_bfloat16 h;
    *(unsigned short*)&h = u;
    return __bfloat162float(h);
}

// transpose + hi/lo split: X [R][N] fp32 -> Thi/Tlo [N][R] bf16 (batched over z)
__global__ __launch_bounds__(256) void transpose_split(
    const float* __restrict__ X, unsigned short* __restrict__ Thi,
    unsigned short* __restrict__ Tlo, int R, int N)
{
    X   += (long)blockIdx.z * R * N;
    Thi += (long)blockIdx.z * N * R;
    Tlo += (long)blockIdx.z * N * R;
    __shared__ float s[32][33];
    const int tx = threadIdx.x & 31, ty = threadIdx.x >> 5;
    const int n0 = blockIdx.x * 32, r0 = blockIdx.y * 32;
#pragma unroll
    for (int r = 0; r < 4; ++r)
        s[ty + r * 8][tx] = X[(long)(r0 + ty + r * 8) * N + n0 + tx];
    __syncthreads();
#pragma unroll
    for (int r = 0; r < 4; ++r) {
        const int n = ty + r * 8;
        const float v = s[tx][n];
        const unsigned short hi = f2bf(v);
        const unsigned short lo = f2bf(v - bf2f(hi));
        Thi[(long)(n0 + n) * R + r0 + tx] = hi;
        Tlo[(long)(n0 + n) * R + r0 + tx] = lo;
    }
}

// concat [Wth; Wph] rows and hi/lo split: out [2P][C]
__global__ __launch_bounds__(256) void split_w2(
    const float* __restrict__ Wth, const float* __restrict__ Wph,
    unsigned short* __restrict__ Whi, unsigned short* __restrict__ Wlo, int PC)
{
    const int i = blockIdx.x * 256 + threadIdx.x;
    if (i < 2 * PC) {
        const float v = (i < PC) ? Wth[i] : Wph[i - PC];
        const unsigned short hi = f2bf(v);
        Whi[i] = hi;
        Wlo[i] = f2bf(v - bf2f(hi));
    }
}

__global__ __launch_bounds__(256) void cast_bf16(
    const float* __restrict__ X, unsigned short* __restrict__ Y)
{
    const long i = ((long)blockIdx.x * 256 + threadIdx.x) * 4;
    const float4 v = *(const float4*)&X[i];
    ushort4 o;
    o.x = f2bf(v.x); o.y = f2bf(v.y); o.z = f2bf(v.z); o.w = f2bf(v.w);
    *(ushort4*)&Y[i] = o;
}

// ---------------- MFMA GEMM (register-prefetch pipeline, round 7) ----------------
// C[M][N] = A[M][K] * B[N][K]^T, bf16 K-contiguous inputs, fp32 accum.
// OUTMODE: 0 fp32, 1 bf16, 2 hi/lo split bf16, 3 bf16 + BN partials scratch
//          (slot = (bz*gridDim.x+bx)*2 + (wn>>6); [C][256] scratch).
#define BK 32

template <bool SPLIT, int OUTMODE, int FM, int FN>
__global__ __launch_bounds__(256) void mfma_gemm(
    const unsigned short* __restrict__ Ahi, const unsigned short* __restrict__ Alo,
    const unsigned short* __restrict__ Bhi, const unsigned short* __restrict__ Blo,
    void* __restrict__ Cout, void* __restrict__ Cout2,
    int K, int lda, int ldb, int ldc,
    long sA, long sB, long sC,
    float* __restrict__ S1, float* __restrict__ S2)
{
    constexpr int MTM = FM * 32, MTN = FN * 32;
    constexpr int SA = FM / 2, SB = FN / 2;

    Ahi += (long)blockIdx.z * sA;
    Bhi += (long)blockIdx.z * sB;
    if (SPLIT) { Alo += (long)blockIdx.z * sA; Blo += (long)blockIdx.z * sB; }
    float* Cf = (float*)Cout + (long)blockIdx.z * sC;
    unsigned short* Ch = (unsigned short*)Cout + (long)blockIdx.z * sC;
    unsigned short* Cl = (unsigned short*)Cout2 + (long)blockIdx.z * sC;

    __shared__ unsigned short AsH[MTM * BK], BsH[MTN * BK];
    __shared__ unsigned short AsL[SPLIT ? MTM * BK : 8], BsL[SPLIT ? MTN * BK : 8];

    const int tid = threadIdx.x;
    const int wid = tid >> 6, lane = tid & 63;
    const int wm = (wid >> 1) * (FM * 16), wn = (wid & 1) * (FN * 16);
    const int l15 = lane & 15, quad = lane >> 4;
    const int m0 = blockIdx.y * MTM, n0 = blockIdx.x * MTN;

    int arow[SA], acol[SA], brow[SB], bcol[SB];
#pragma unroll
    for (int t = 0; t < SA; ++t) {
        const int gid = t * 256 + tid;
        arow[t] = gid >> 2; acol[t] = (gid & 3) * 8;
    }
#pragma unroll
    for (int t = 0; t < SB; ++t) {
        const int gid = t * 256 + tid;
        brow[t] = gid >> 2; bcol[t] = (gid & 3) * 8;
    }

    short8 pa[SA], pb[SB], paL[SPLIT ? SA : 1], pbL[SPLIT ? SB : 1];

    auto loadTiles = [&](int k0) {
#pragma unroll
        for (int t = 0; t < SA; ++t) {
            const long o = (long)(m0 + arow[t]) * lda + k0 + acol[t];
            pa[t] = *(const short8*)&Ahi[o];
            if (SPLIT) paL[t] = *(const short8*)&Alo[o];
        }
#pragma unroll
        for (int t = 0; t < SB; ++t) {
            const long o = (long)(n0 + brow[t]) * ldb + k0 + bcol[t];
            pb[t] = *(const short8*)&Bhi[o];
            if (SPLIT) pbL[t] = *(const short8*)&Blo[o];
        }
    };
    auto writeTiles = [&]() {
#pragma unroll
        for (int t = 0; t < SA; ++t) {
            *(short8*)&AsH[arow[t] * BK + acol[t]] = pa[t];
            if (SPLIT) *(short8*)&AsL[arow[t] * BK + acol[t]] = paL[t];
        }
#pragma unroll
        for (int t = 0; t < SB; ++t) {
            *(short8*)&BsH[brow[t] * BK + bcol[t]] = pb[t];
            if (SPLIT) *(short8*)&BsL[brow[t] * BK + bcol[t]] = pbL[t];
        }
    };

    floatx4 acc[FM][FN];
#pragma unroll
    for (int i = 0; i < FM; ++i)
#pragma unroll
        for (int j = 0; j < FN; ++j) acc[i][j] = (floatx4){0.f, 0.f, 0.f, 0.f};

    const int iters = K / BK;
    loadTiles(0);
    writeTiles();
    __syncthreads();

    for (int it = 0; it < iters; ++it) {
        if (it + 1 < iters) loadTiles((it + 1) * BK);

        short8 ah[FM], bh[FN], al[SPLIT ? FM : 1], bl[SPLIT ? FN : 1];
#pragma unroll
        for (int i = 0; i < FM; ++i) {
            ah[i] = *(const short8*)&AsH[(wm + i * 16 + l15) * BK + quad * 8];
            if (SPLIT) al[i] = *(const short8*)&AsL[(wm + i * 16 + l15) * BK + quad * 8];
        }
#pragma unroll
        for (int j = 0; j < FN; ++j) {
            bh[j] = *(const short8*)&BsH[(wn + j * 16 + l15) * BK + quad * 8];
            if (SPLIT) bl[j] = *(const short8*)&BsL[(wn + j * 16 + l15) * BK + quad * 8];
        }
#pragma unroll
        for (int i = 0; i < FM; ++i)
#pragma unroll
            for (int j = 0; j < FN; ++j) {
                acc[i][j] = __builtin_amdgcn_mfma_f32_16x16x32_bf16(ah[i], bh[j], acc[i][j], 0, 0, 0);
                if (SPLIT) {
                    acc[i][j] = __builtin_amdgcn_mfma_f32_16x16x32_bf16(ah[i], bl[j], acc[i][j], 0, 0, 0);
                    acc[i][j] = __builtin_amdgcn_mfma_f32_16x16x32_bf16(al[i], bh[j], acc[i][j], 0, 0, 0);
                }
            }

        if (it + 1 < iters) {
            __syncthreads();
            writeTiles();
            __syncthreads();
        }
    }

#pragma unroll
    for (int i = 0; i < FM; ++i)
#pragma unroll
        for (int j = 0; j < FN; ++j) {
            const int m = m0 + wm + i * 16 + quad * 4;
            const int n = n0 + wn + j * 16 + l15;
#pragma unroll
            for (int r = 0; r < 4; ++r) {
                const float v = acc[i][j][r];
                const long idx = (long)(m + r) * ldc + n;
                if (OUTMODE == 0) {
                    Cf[idx] = v;
                } else if (OUTMODE == 1 || OUTMODE == 3) {
                    Ch[idx] = f2bf(v);
                } else {
                    const unsigned short hi = f2bf(v);
                    Ch[idx] = hi;
                    Cl[idx] = f2bf(v - bf2f(hi));
                }
            }
        }

    if (OUTMODE == 3) {
        const int slot = (blockIdx.z * gridDim.x + blockIdx.x) * 2 + (wn >> 6);
#pragma unroll
        for (int i = 0; i < FM; ++i)
#pragma unroll
            for (int r = 0; r < 4; ++r) {
                float s = 0.f, q = 0.f;
#pragma unroll
                for (int j = 0; j < FN; ++j) {
                    const float v = acc[i][j][r];
                    s += v; q += v * v;
                }
#pragma unroll
                for (int msk = 1; msk < 16; msk <<= 1) {
                    s += __shfl_xor(s, msk, 64);
                    q += __shfl_xor(q, msk, 64);
                }
                if (l15 == 0) {
                    const int row = m0 + wm + i * 16 + quad * 4 + r;
                    S1[(long)row * 256 + slot] = s;
                    S2[(long)row * 256 + slot] = q;
                }
            }
    }
}

// ---------------- fused scores+softmax+y v3.1 (split-K x4, 4 blocks/CU) ----------------
// 1024 blocks (b = id&7, kh = (id>>3)&3, qt = id>>5), 4 waves; wave owns 16 q-rows.
// Block processes keys [kh*512, +512) (4 tiles of 128) with online-softmax state;
// writes self-normalized fp32 partial y + (m,l) per row (4 partials total).
// LDS: phi hi/lo staged in 32-c chunks (2*128*40 shorts) ALIASED with
// G staged in 32-key chunks (256*40 shorts) = 20,480 B; + Pw 17,408 B
// -> 37,888 B/block -> 4 blocks/CU (16 waves/CU, 4/SIMD).
#define FSTR 40     // phi LDS row stride (32 c + 8 pad)
#define GSTR 40     // G   LDS row stride (32 keys + 8 pad)
#define PSTRP 136   // P   LDS row stride (128 keys + 8 pad)

__global__ __launch_bounds__(256, 4) void fused_attn(
    const unsigned short* __restrict__ thphH,
    const unsigned short* __restrict__ thphL,
    const unsigned short* __restrict__ gbf,
    float* __restrict__ yp,       // [4][B][N][P] fp32 partials (self-normalized)
    float2* __restrict__ ml)      // [4][B*N] {m, l}
{
    const int N = 2048, P = 256, P2 = 512;
    const int id = blockIdx.x;
    const int b  = id & 7;            // XCD-locality heuristic
    const int kh = (id >> 3) & 3;     // key quarter
    const int qt = id >> 5;           // 0..31
    const int q0 = qt * 64;

    const unsigned short* thB = thphH + (long)b * N * P2;
    const unsigned short* tlB = thphL + (long)b * N * P2;
    const unsigned short* gB  = gbf   + (long)b * P * N;
    float*  ypB = yp + (long)kh * (8L * N * P) + (long)b * N * P;
    float2* mlB = ml + (long)kh * (8L * N) + (long)b * N;

    // phi hi/lo and G share the same LDS (disjoint phases, fenced below)
    __shared__ unsigned short FG[2 * 128 * FSTR];     // 10240 shorts = 20,480 B
    unsigned short* Fh = FG;                          // 128*FSTR
    unsigned short* Fl = FG + 128 * FSTR;             // 128*FSTR
    unsigned short* Gs = FG;                          // 256*GSTR == 2*128*FSTR
    __shared__ unsigned short Pw[4][16 * PSTRP];      // wave-private P

    const int tid = threadIdx.x;
    const int wid = tid >> 6, lane = tid & 63;
    const int l15 = lane & 15, quad = lane >> 4;

    // theta fragments in registers: wave rows [q0+wid*16, +16), A m = l15
    short8 tHr[8], tLr[8];
    {
        const unsigned short* t1 = thB + (long)(q0 + wid * 16 + l15) * P2;
        const unsigned short* t2 = tlB + (long)(q0 + wid * 16 + l15) * P2;
#pragma unroll
        for (int kt = 0; kt < 8; ++kt) {
            tHr[kt] = *(const short8*)&t1[kt * 32 + quad * 8];
            tLr[kt] = *(const short8*)&t2[kt * 32 + quad * 8];
        }
    }

    float mrun[4], lrun[4];
#pragma unroll
    for (int r = 0; r < 4; ++r) { mrun[r] = -1e30f; lrun[r] = 0.f; }

    floatx4 oacc[16];
#pragma unroll
    for (int p = 0; p < 16; ++p) oacc[p] = (floatx4){0.f, 0.f, 0.f, 0.f};

    // staging: 32-short rows -> 4 threads/row; prow = tid>>2, pc8 = (tid&3)*8
    const int prow = tid >> 2, pc8 = (tid & 3) * 8;
    short8 pfH[2], pfL[2], pg[4];

    auto loadPhi = [&](int m0, int kc) {
#pragma unroll
        for (int s = 0; s < 2; ++s) {
            const long o = (long)(m0 + prow + s * 64) * P2 + P + kc * 32 + pc8;
            pfH[s] = *(const short8*)&thB[o];
            pfL[s] = *(const short8*)&tlB[o];
        }
    };
    auto writePhi = [&]() {
#pragma unroll
        for (int s = 0; s < 2; ++s) {
            *(short8*)&Fh[(prow + s * 64) * FSTR + pc8] = pfH[s];
            *(short8*)&Fl[(prow + s * 64) * FSTR + pc8] = pfL[s];
        }
    };
    auto loadG = [&](int m0, int mc) {
#pragma unroll
        for (int s = 0; s < 4; ++s)
            pg[s] = *(const short8*)&gB[(long)(prow + s * 64) * N + m0 + mc * 32 + pc8];
    };
    auto writeG = [&]() {
#pragma unroll
        for (int s = 0; s < 4; ++s)
            *(short8*)&Gs[(prow + s * 64) * GSTR + pc8] = pg[s];
    };

    for (int mt = 0; mt < 4; ++mt) {
        const int m0 = kh * 512 + mt * 128;

        // ---- S phase: 8 chunks of 32 c ----
        floatx4 sacc[8];
#pragma unroll
        for (int j = 0; j < 8; ++j) sacc[j] = (floatx4){0.f, 0.f, 0.f, 0.f};

        loadPhi(m0, 0);
        __syncthreads();            // all waves done reading Gs (prev PV) — alias fence
        writePhi();
        __syncthreads();
#pragma unroll
        for (int kc = 0; kc < 8; ++kc) {
            if (kc < 7) loadPhi(m0, kc + 1);       // prefetch flies over MFMAs
            const short8 aH = tHr[kc];
            const short8 aL = tLr[kc];
#pragma unroll
            for (int j = 0; j < 8; ++j) {
                const int ro = (j * 16 + l15) * FSTR + quad * 8;
                const short8 bh = *(const short8*)&Fh[ro];
                const short8 bl = *(const short8*)&Fl[ro];
                sacc[j] = __builtin_amdgcn_mfma_f32_16x16x32_bf16(aH, bh, sacc[j], 0, 0, 0);
                sacc[j] = __builtin_amdgcn_mfma_f32_16x16x32_bf16(aH, bl, sacc[j], 0, 0, 0);
                sacc[j] = __builtin_amdgcn_mfma_f32_16x16x32_bf16(aL, bh, sacc[j], 0, 0, 0);
            }
            if (kc < 7) {
                __syncthreads();
                writePhi();                         // vmcnt wait lands here
                __syncthreads();
            }
        }

        // ---- online softmax (registers only; rows = quad*4+r) ----
        float alpha[4];
#pragma unroll
        for (int r = 0; r < 4; ++r) {
            float v = sacc[0][r];
#pragma unroll
            for (int j = 1; j < 8; ++j) v = fmaxf(v, sacc[j][r]);
            v = fmaxf(v, __shfl_xor(v, 1, 64));
            v = fmaxf(v, __shfl_xor(v, 2, 64));
            v = fmaxf(v, __shfl_xor(v, 4, 64));
            v = fmaxf(v, __shfl_xor(v, 8, 64));
            const float mo = mrun[r];
            const float mn = fmaxf(mo, v);
            mrun[r] = mn;
            alpha[r] = __expf(mo - mn);
        }
        float lpart[4] = {0.f, 0.f, 0.f, 0.f};
#pragma unroll
        for (int j = 0; j < 8; ++j)
#pragma unroll
            for (int r = 0; r < 4; ++r) {
                const float p = __expf(sacc[j][r] - mrun[r]);
                Pw[wid][(quad * 4 + r) * PSTRP + j * 16 + l15] = f2bf(p);
                lpart[r] += p;
            }
#pragma unroll
        for (int r = 0; r < 4; ++r) {
            float s = lpart[r];
            s += __shfl_xor(s, 1, 64);
            s += __shfl_xor(s, 2, 64);
            s += __shfl_xor(s, 4, 64);
            s += __shfl_xor(s, 8, 64);
            lrun[r] = lrun[r] * alpha[r] + s;
        }
        {
            const int noresc = (alpha[0] == 1.f) & (alpha[1] == 1.f) &
                               (alpha[2] == 1.f) & (alpha[3] == 1.f);
            if (!__all(noresc)) {
#pragma unroll
                for (int p = 0; p < 16; ++p)
#pragma unroll
                    for (int r = 0; r < 4; ++r) oacc[p][r] *= alpha[r];
            }
        }

        // ---- PV phase: 4 chunks of 32 keys ----
        loadG(m0, 0);
        __syncthreads();            // all waves done reading Fh/Fl — alias fence
        writeG();
        __syncthreads();
#pragma unroll
        for (int mc = 0; mc < 4; ++mc) {
            if (mc < 3) loadG(m0, mc + 1);         // prefetch
            const short8 af = *(const short8*)&Pw[wid][l15 * PSTRP + mc * 32 + quad * 8];
#pragma unroll
            for (int pj = 0; pj < 16; ++pj) {
                const short8 bg = *(const short8*)&Gs[(pj * 16 + l15) * GSTR + quad * 8];
                oacc[pj] = __builtin_amdgcn_mfma_f32_16x16x32_bf16(af, bg, oacc[pj], 0, 0, 0);
            }
            if (mc < 3) {
                __syncthreads();
                writeG();
                __syncthreads();
            }
        }
    }

    // ---- finalize: self-normalized fp32 partial + (m,l) per row ----
    float linv[4];
#pragma unroll
    for (int r = 0; r < 4; ++r) linv[r] = 1.0f / lrun[r];
#pragma unroll
    for (int pj = 0; pj < 16; ++pj)
#pragma unroll
        for (int r = 0; r < 4; ++r) {
            const int row = q0 + wid * 16 + quad * 4 + r;
            const int col = pj * 16 + l15;
            ypB[(long)row * P + col] = oacc[pj][r] * linv[r];
        }
    if (l15 == 0) {
#pragma unroll
        for (int r = 0; r < 4; ++r) {
            const int row = q0 + wid * 16 + quad * 4 + r;
            mlB[row] = float2{mrun[r], lrun[r]};
        }
    }
}

// merge the four key-quarter partials: y = sum f_k*y_k, f_k = l_k e^{m_k-m}/Z
__global__ __launch_bounds__(256) void attn_merge(
    const float* __restrict__ yp, const float2* __restrict__ ml,
    unsigned short* __restrict__ ybf)
{
    const long STRIDE = 8L * 2048 * 256;   // per-partial stride (floats)
    const long NROWS  = 8L * 2048;
    const long t = (long)blockIdx.x * 256 + threadIdx.x;
    const long row = t >> 5;
    const int  c0  = ((int)t & 31) * 8;
    const float2 a0 = ml[row];
    const float2 a1 = ml[NROWS + row];
    const float2 a2 = ml[2 * NROWS + row];
    const float2 a3 = ml[3 * NROWS + row];
    const float mx = fmaxf(fmaxf(a0.x, a1.x), fmaxf(a2.x, a3.x));
    const float w0 = a0.y * __expf(a0.x - mx);
    const float w1 = a1.y * __expf(a1.x - mx);
    const float w2 = a2.y * __expf(a2.x - mx);
    const float w3 = a3.y * __expf(a3.x - mx);
    const float inv = 1.0f / (w0 + w1 + w2 + w3);
    const float f0 = w0 * inv, f1 = w1 * inv, f2 = w2 * inv, f3 = w3 * inv;
    const long base = row * 256 + c0;
    const float4 u0 = *(const float4*)&yp[base];
    const float4 u1 = *(const float4*)&yp[base + 4];
    const float4 v0 = *(const float4*)&yp[STRIDE + base];
    const float4 v1 = *(const float4*)&yp[STRIDE + base + 4];
    const float4 p0 = *(const float4*)&yp[2 * STRIDE + base];
    const float4 p1 = *(const float4*)&yp[2 * STRIDE + base + 4];
    const float4 q0 = *(const float4*)&yp[3 * STRIDE + base];
    const float4 q1 = *(const float4*)&yp[3 * STRIDE + base + 4];
    ushort4 o0, o1;
    o0.x = f2bf(f0 * u0.x + f1 * v0.x + f2 * p0.x + f3 * q0.x);
    o0.y = f2bf(f0 * u0.y + f1 * v0.y + f2 * p0.y + f3 * q0.y);
    o0.z = f2bf(f0 * u0.z + f1 * v0.z + f2 * p0.z + f3 * q0.z);
    o0.w = f2bf(f0 * u0.w + f1 * v0.w + f2 * p0.w + f3 * q0.w);
    o1.x = f2bf(f0 * u1.x + f1 * v1.x + f2 * p1.x + f3 * q1.x);
    o1.y = f2bf(f0 * u1.y + f1 * v1.y + f2 * p1.y + f3 * q1.y);
    o1.z = f2bf(f0 * u1.z + f1 * v1.z + f2 * p1.z + f3 * q1.z);
    o1.w = f2bf(f0 * u1.w + f1 * v1.w + f2 * p1.w + f3 * q1.w);
    *(ushort4*)&ybf[base] = o0;
    *(ushort4*)&ybf[base + 4] = o1;
}

// ---------------- BN finalize + apply ----------------
__global__ __launch_bounds__(256) void bn_finalize(
    const float* __restrict__ p1, const float* __restrict__ p2,
    float* __restrict__ mean, float* __restrict__ rstd, float cnt)
{
    const int c = blockIdx.x, t = threadIdx.x;
    __shared__ float rs[256], rq[256];
    rs[t] = p1[(long)c * 256 + t];
    rq[t] = p2[(long)c * 256 + t];
    __syncthreads();
    for (int st = 128; st > 0; st >>= 1) {
        if (t < st) { rs[t] += rs[t + st]; rq[t] += rq[t + st]; }
        __syncthreads();
    }
    if (t == 0) {
        const float m = rs[0] / cnt;
        mean[c] = m;
        rstd[c] = rsqrtf(rq[0] / cnt - m * m + 1e-5f);
    }
}

__global__ __launch_bounds__(256) void bn_apply_bf(
    const unsigned short* __restrict__ z, const float* __restrict__ x,
    const float* __restrict__ mean, const float* __restrict__ rstd,
    const float* __restrict__ gamma, const float* __restrict__ beta,
    float* __restrict__ out, int C, int N)
{
    const long i = ((long)blockIdx.x * 256 + threadIdx.x) * 8;
    const int c = (int)((i / N) % C);
    const float mu = mean[c], rs = rstd[c], ga = gamma[c], be = beta[c];
    const ushort4 z0 = *(const ushort4*)&z[i];
    const ushort4 z1 = *(const ushort4*)&z[i + 4];
    const float4 x0 = *(const float4*)&x[i];
    const float4 x1 = *(const float4*)&x[i + 4];
    float4 o0, o1;
    o0.x = (bf2f(z0.x) - mu) * rs * ga + be + x0.x;
    o0.y = (bf2f(z0.y) - mu) * rs * ga + be + x0.y;
    o0.z = (bf2f(z0.z) - mu) * rs * ga + be + x0.z;
    o0.w = (bf2f(z0.w) - mu) * rs * ga + be + x0.w;
    o1.x = (bf2f(z1.x) - mu) * rs * ga + be + x1.x;
    o1.y = (bf2f(z1.y) - mu) * rs * ga + be + x1.y;
    o1.z = (bf2f(z1.z) - mu) * rs * ga + be + x1.z;
    o1.w = (bf2f(z1.w) - mu) * rs * ga + be + x1.w;
    *(float4*)&out[i] = o0;
    *(float4*)&out[i + 4] = o1;
}

extern "C" void kernel_launch(void* const* d_in, const int* in_sizes, int n_in,
                              void* d_out, int out_size, void* d_ws, size_t ws_size,
                              hipStream_t stream)
{
    const int B = 8, C = 512, N = 2048, P = 256;
    const float* x      = (const float*)d_in[0];
    const float* Wg     = (const float*)d_in[1];
    const float* Wtheta = (const float*)d_in[2];
    const float* Wphi   = (const float*)d_in[3];
    const float* Wz     = (const float*)d_in[4];
    const float* gamma  = (const float*)d_in[5];
    const float* beta   = (const float*)d_in[6];
    float* out = (float*)d_out;

    // ---- workspace layout (float units), same as round 9 ----
    float* ws = (float*)d_ws;
    const long NCle = (long)N * C;            // 1,048,576 per batch (= N*2P)
    const long NP   = (long)N * P;            // 524,288 per batch
    const long R0   = (long)B * NCle;         // 8.39M floats
    unsigned short* xtH   = (unsigned short*)ws;                // B*N*C
    unsigned short* xtL   = xtH + B * NCle;
    unsigned short* zbf   = (unsigned short*)ws;                // aliases xt (dead)
    unsigned short* thphH = (unsigned short*)(ws + R0);         // B*N*2P
    unsigned short* thphL = thphH + B * NCle;                   // B*N*2P
    unsigned short* gbf   = (unsigned short*)(ws + 2 * R0);     // B*P*N
    unsigned short* fbf   = gbf + B * NP;                       // attn partial region
    unsigned short* ybf   = fbf + (long)B * N * N;              // B*N*P
    unsigned short* W2H   = ybf + B * NP;                       // 2P*C
    unsigned short* W2L   = W2H + 2L * P * C;
    unsigned short* WgB   = W2L + 2L * P * C;                   // P*C
    unsigned short* WzB   = WgB + (long)P * C;
    // attn split-K partials: yp[4] exactly fills the dead fbf region
    // (4 * B*N*P floats == B*N*N shorts); ml lives in the dead xtL region
    // (xtL is free after GEMM #4; zbf only spans the xtH half [0, 4.2M floats)).
    float*          yp    = (float*)fbf;                        // [4][B][N][P] fp32
    float2*         ml    = (float2*)(ws + 6L * 1024 * 1024);   // [4][B*N], in xtL
    // BN scratch aliases thph region (dead after fused_attn): [C][256] x2
    float*          bnp1  = ws + R0;
    float*          bnp2  = bnp1 + (long)C * 256;
    float*          mean  = bnp2 + (long)C * 256;
    float*          rstd  = mean + C;

    const long sX = (long)C * N;
    const int  P2 = 2 * P;

    // 1: transpose+split x -> xT hi/lo [B][N][C]
    transpose_split<<<dim3(N / 32, C / 32, B), 256, 0, stream>>>(x, xtH, xtL, C, N);
    // 2: weight preps
    split_w2<<<(2 * P * C + 255) / 256, 256, 0, stream>>>(Wtheta, Wphi, W2H, W2L, P * C);
    cast_bf16<<<P * C / 1024, 256, 0, stream>>>(Wg, WgB);
    cast_bf16<<<P * C / 1024, 256, 0, stream>>>(Wz, WzB);

    // 3: thph [B][N][2P] = xT @ W2^T (split in/out); 128x128, 512 blocks
    mfma_gemm<true, 2, 4, 4><<<dim3(P2 / 128, N / 128, B), 256, 0, stream>>>(
        xtH, xtL, W2H, W2L, thphH, thphL, C, C, C, P2, NCle, 0, NCle, nullptr, nullptr);
    // 4: g [B][P][N] = Wg @ xT^T (plain, bf16 out); 64x128, 512 blocks
    mfma_gemm<false, 1, 2, 4><<<dim3(N / 128, P / 64, B), 256, 0, stream>>>(
        WgB, WgB, xtH, xtH, gbf, gbf, C, C, C, N, 0, NCle, NP, nullptr, nullptr);

    // 5: fused scores+softmax+y, split-K x4 over keys (1024 blocks, 4/CU) + merge
    fused_attn<<<dim3(1024), 256, 0, stream>>>(thphH, thphL, gbf, yp, ml);
    attn_merge<<<dim3(2048), 256, 0, stream>>>(yp, ml, ybf);

    // 6: z [B][C][N] bf16 = Wz @ yT^T, BN partials (thph dead now)
    mfma_gemm<false, 3, 4, 4><<<dim3(N / 128, C / 128, B), 256, 0, stream>>>(
        WzB, WzB, ybf, ybf, zbf, zbf, P, P, P, N, 0, NP, sX, bnp1, bnp2);

    // 7: BN finalize + apply + residual
    bn_finalize<<<C, 256, 0, stream>>>(bnp1, bnp2, mean, rstd, (float)B * N);
    bn_apply_bf<<<(int)((B * sX) / 2048), 256, 0, stream>>>(zbf, x, mean, rstd, gamma, beta, out, C, N);
}

// Round 3
// 288.318 us; speedup vs baseline: 1.4274x; 1.4274x over previous
//
#include <hip/hip_runtime.h>
#include <hip/hip_bf16.h>

// B=8, C=512, N=2048, P=256.
// Round 13: recover from R2 spill disaster (launch_bounds(256,4) -> 64 VGPR ->
// 730MB scratch traffic). Back to natural 128-VGPR body, plus:
//   - kh=4 split, grid 1024, LDS 50,432B -> 3 blocks/CU resident (R1 was
//     grid-limited to 2/CU, not LDS-limited).
//   - square PV tiling: wave computes 64q x 64p (was 16q x 256p) -> PV LDS
//     reads 68 -> 32 b128/wave/tile (2x fragment reuse both operands).
//     Cross-wave Pw reads (already shared; existing barriers order it);
//     alpha / 1/l published via 64-float LDS buffer.
//   - phi/G buffer unpadded stride-64 + T2 XOR swizzle (slot ^= row&7 on 16B
//     granules, same swizzle write+read) -> conflict-free, FG 36.9->32.8KB.
// Predicted: VGPR ~128-160, Occ 20->35%, MfmaUtil 26->~40, fused 110->~75us.

typedef __attribute__((ext_vector_type(8))) short short8;
typedef __attribute__((ext_vector_type(4))) float floatx4;

// ---------------- bf16 helpers ----------------
__device__ __forceinline__ unsigned short f2bf(float v) {
    __hip_bfloat16 h = __float2bfloat16(v);
    return *(unsigned short*)&h;
}
__device__ __forceinline__ float bf2f(unsigned short u) {
    __hip_bfloat16 h;
    *(unsigned short*)&h = u;
    return __bfloat162float(h);
}

// transpose + hi/lo split: X [R][N] fp32 -> Thi/Tlo [N][R] bf16 (batched over z)
__global__ __launch_bounds__(256) void transpose_split(
    const float* __restrict__ X, unsigned short* __restrict__ Thi,
    unsigned short* __restrict__ Tlo, int R, int N)
{
    X   += (long)blockIdx.z * R * N;
    Thi += (long)blockIdx.z * N * R;
    Tlo += (long)blockIdx.z * N * R;
    __shared__ float s[32][33];
    const int tx = threadIdx.x & 31, ty = threadIdx.x >> 5;
    const int n0 = blockIdx.x * 32, r0 = blockIdx.y * 32;
#pragma unroll
    for (int r = 0; r < 4; ++r)
        s[ty + r * 8][tx] = X[(long)(r0 + ty + r * 8) * N + n0 + tx];
    __syncthreads();
#pragma unroll
    for (int r = 0; r < 4; ++r) {
        const int n = ty + r * 8;
        const float v = s[tx][n];
        const unsigned short hi = f2bf(v);
        const unsigned short lo = f2bf(v - bf2f(hi));
        Thi[(long)(n0 + n) * R + r0 + tx] = hi;
        Tlo[(long)(n0 + n) * R + r0 + tx] = lo;
    }
}

// concat [Wth; Wph] rows and hi/lo split: out [2P][C]
__global__ __launch_bounds__(256) void split_w2(
    const float* __restrict__ Wth, const float* __restrict__ Wph,
    unsigned short* __restrict__ Whi, unsigned short* __restrict__ Wlo, int PC)
{
    const int i = blockIdx.x * 256 + threadIdx.x;
    if (i < 2 * PC) {
        const float v = (i < PC) ? Wth[i] : Wph[i - PC];
        const unsigned short hi = f2bf(v);
        Whi[i] = hi;
        Wlo[i] = f2bf(v - bf2f(hi));
    }
}

__global__ __launch_bounds__(256) void cast_bf16(
    const float* __restrict__ X, unsigned short* __restrict__ Y)
{
    const long i = ((long)blockIdx.x * 256 + threadIdx.x) * 4;
    const float4 v = *(const float4*)&X[i];
    ushort4 o;
    o.x = f2bf(v.x); o.y = f2bf(v.y); o.z = f2bf(v.z); o.w = f2bf(v.w);
    *(ushort4*)&Y[i] = o;
}

// ---------------- MFMA GEMM (register-prefetch pipeline, round 7) ----------------
// C[M][N] = A[M][K] * B[N][K]^T, bf16 K-contiguous inputs, fp32 accum.
// OUTMODE: 0 fp32, 1 bf16, 2 hi/lo split bf16, 3 bf16 + BN partials scratch
//          (slot = (bz*gridDim.x+bx)*2 + (wn>>6); [C][256] scratch).
#define BK 32

template <bool SPLIT, int OUTMODE, int FM, int FN>
__global__ __launch_bounds__(256) void mfma_gemm(
    const unsigned short* __restrict__ Ahi, const unsigned short* __restrict__ Alo,
    const unsigned short* __restrict__ Bhi, const unsigned short* __restrict__ Blo,
    void* __restrict__ Cout, void* __restrict__ Cout2,
    int K, int lda, int ldb, int ldc,
    long sA, long sB, long sC,
    float* __restrict__ S1, float* __restrict__ S2)
{
    constexpr int MTM = FM * 32, MTN = FN * 32;
    constexpr int SA = FM / 2, SB = FN / 2;

    Ahi += (long)blockIdx.z * sA;
    Bhi += (long)blockIdx.z * sB;
    if (SPLIT) { Alo += (long)blockIdx.z * sA; Blo += (long)blockIdx.z * sB; }
    float* Cf = (float*)Cout + (long)blockIdx.z * sC;
    unsigned short* Ch = (unsigned short*)Cout + (long)blockIdx.z * sC;
    unsigned short* Cl = (unsigned short*)Cout2 + (long)blockIdx.z * sC;

    __shared__ unsigned short AsH[MTM * BK], BsH[MTN * BK];
    __shared__ unsigned short AsL[SPLIT ? MTM * BK : 8], BsL[SPLIT ? MTN * BK : 8];

    const int tid = threadIdx.x;
    const int wid = tid >> 6, lane = tid & 63;
    const int wm = (wid >> 1) * (FM * 16), wn = (wid & 1) * (FN * 16);
    const int l15 = lane & 15, quad = lane >> 4;
    const int m0 = blockIdx.y * MTM, n0 = blockIdx.x * MTN;

    int arow[SA], acol[SA], brow[SB], bcol[SB];
#pragma unroll
    for (int t = 0; t < SA; ++t) {
        const int gid = t * 256 + tid;
        arow[t] = gid >> 2; acol[t] = (gid & 3) * 8;
    }
#pragma unroll
    for (int t = 0; t < SB; ++t) {
        const int gid = t * 256 + tid;
        brow[t] = gid >> 2; bcol[t] = (gid & 3) * 8;
    }

    short8 pa[SA], pb[SB], paL[SPLIT ? SA : 1], pbL[SPLIT ? SB : 1];

    auto loadTiles = [&](int k0) {
#pragma unroll
        for (int t = 0; t < SA; ++t) {
            const long o = (long)(m0 + arow[t]) * lda + k0 + acol[t];
            pa[t] = *(const short8*)&Ahi[o];
            if (SPLIT) paL[t] = *(const short8*)&Alo[o];
        }
#pragma unroll
        for (int t = 0; t < SB; ++t) {
            const long o = (long)(n0 + brow[t]) * ldb + k0 + bcol[t];
            pb[t] = *(const short8*)&Bhi[o];
            if (SPLIT) pbL[t] = *(const short8*)&Blo[o];
        }
    };
    auto writeTiles = [&]() {
#pragma unroll
        for (int t = 0; t < SA; ++t) {
            *(short8*)&AsH[arow[t] * BK + acol[t]] = pa[t];
            if (SPLIT) *(short8*)&AsL[arow[t] * BK + acol[t]] = paL[t];
        }
#pragma unroll
        for (int t = 0; t < SB; ++t) {
            *(short8*)&BsH[brow[t] * BK + bcol[t]] = pb[t];
            if (SPLIT) *(short8*)&BsL[brow[t] * BK + bcol[t]] = pbL[t];
        }
    };

    floatx4 acc[FM][FN];
#pragma unroll
    for (int i = 0; i < FM; ++i)
#pragma unroll
        for (int j = 0; j < FN; ++j) acc[i][j] = (floatx4){0.f, 0.f, 0.f, 0.f};

    const int iters = K / BK;
    loadTiles(0);
    writeTiles();
    __syncthreads();

    for (int it = 0; it < iters; ++it) {
        if (it + 1 < iters) loadTiles((it + 1) * BK);

        short8 ah[FM], bh[FN], al[SPLIT ? FM : 1], bl[SPLIT ? FN : 1];
#pragma unroll
        for (int i = 0; i < FM; ++i) {
            ah[i] = *(const short8*)&AsH[(wm + i * 16 + l15) * BK + quad * 8];
            if (SPLIT) al[i] = *(const short8*)&AsL[(wm + i * 16 + l15) * BK + quad * 8];
        }
#pragma unroll
        for (int j = 0; j < FN; ++j) {
            bh[j] = *(const short8*)&BsH[(wn + j * 16 + l15) * BK + quad * 8];
            if (SPLIT) bl[j] = *(const short8*)&BsL[(wn + j * 16 + l15) * BK + quad * 8];
        }
#pragma unroll
        for (int i = 0; i < FM; ++i)
#pragma unroll
            for (int j = 0; j < FN; ++j) {
                acc[i][j] = __builtin_amdgcn_mfma_f32_16x16x32_bf16(ah[i], bh[j], acc[i][j], 0, 0, 0);
                if (SPLIT) {
                    acc[i][j] = __builtin_amdgcn_mfma_f32_16x16x32_bf16(ah[i], bl[j], acc[i][j], 0, 0, 0);
                    acc[i][j] = __builtin_amdgcn_mfma_f32_16x16x32_bf16(al[i], bh[j], acc[i][j], 0, 0, 0);
                }
            }

        if (it + 1 < iters) {
            __syncthreads();
            writeTiles();
            __syncthreads();
        }
    }

#pragma unroll
    for (int i = 0; i < FM; ++i)
#pragma unroll
        for (int j = 0; j < FN; ++j) {
            const int m = m0 + wm + i * 16 + quad * 4;
            const int n = n0 + wn + j * 16 + l15;
#pragma unroll
            for (int r = 0; r < 4; ++r) {
                const float v = acc[i][j][r];
                const long idx = (long)(m + r) * ldc + n;
                if (OUTMODE == 0) {
                    Cf[idx] = v;
                } else if (OUTMODE == 1 || OUTMODE == 3) {
                    Ch[idx] = f2bf(v);
                } else {
                    const unsigned short hi = f2bf(v);
                    Ch[idx] = hi;
                    Cl[idx] = f2bf(v - bf2f(hi));
                }
            }
        }

    if (OUTMODE == 3) {
        const int slot = (blockIdx.z * gridDim.x + blockIdx.x) * 2 + (wn >> 6);
#pragma unroll
        for (int i = 0; i < FM; ++i)
#pragma unroll
            for (int r = 0; r < 4; ++r) {
                float s = 0.f, q = 0.f;
#pragma unroll
                for (int j = 0; j < FN; ++j) {
                    const float v = acc[i][j][r];
                    s += v; q += v * v;
                }
#pragma unroll
                for (int msk = 1; msk < 16; msk <<= 1) {
                    s += __shfl_xor(s, msk, 64);
                    q += __shfl_xor(q, msk, 64);
                }
                if (l15 == 0) {
                    const int row = m0 + wm + i * 16 + quad * 4 + r;
                    S1[(long)row * 256 + slot] = s;
                    S2[(long)row * 256 + slot] = q;
                }
            }
    }
}

// ---------------- fused scores+softmax+y v4 ----------------
// 1024 blocks (b = id&7, kh = (id>>3)&3, qt = id>>5), 4 waves.
// S phase: wave owns 16 q-rows (register softmax, as R1).
// PV phase: SQUARE tiling — wave computes all 64 q-rows x its 64-p slice;
//   cross-wave Pw reads (barrier-ordered), alpha/linv via Aly LDS buffer.
// LDS: FG (phi hi/lo | G, aliased) unpadded stride-64 + XOR swizzle 32,768B
//      + Pw 17,408B + Aly 256B = 50,432B -> 3 blocks/CU at grid 1024.
#define PSTRP 136   // P LDS row stride (128 keys + 8 pad)

// swizzled short-offset into a [rows][64-short] tile: 16B slot ^= row&7
__device__ __forceinline__ int swz64(int row, int slot) {
    return (row << 6) + (((slot ^ row) & 7) << 3);
}

__global__ __launch_bounds__(256, 2) void fused_attn(
    const unsigned short* __restrict__ thphH,
    const unsigned short* __restrict__ thphL,
    const unsigned short* __restrict__ gbf,
    float* __restrict__ yp,       // [4][B][N][P] fp32 partials (self-normalized)
    float2* __restrict__ ml)      // [4][B*N] {m, l}
{
    const int N = 2048, P = 256, P2 = 512;
    const int id = blockIdx.x;
    const int b  = id & 7;            // XCD-locality heuristic
    const int kh = (id >> 3) & 3;     // key quarter
    const int qt = id >> 5;           // 0..31
    const int q0 = qt * 64;

    const unsigned short* thB = thphH + (long)b * N * P2;
    const unsigned short* tlB = thphL + (long)b * N * P2;
    const unsigned short* gB  = gbf   + (long)b * P * N;
    float*  ypB = yp + (long)kh * (8L * N * P) + (long)b * N * P;
    float2* mlB = ml + (long)kh * (8L * N) + (long)b * N;

    // phi hi/lo and G share the same LDS (disjoint phases, fenced below)
    __shared__ unsigned short FG[2 * 128 * 64];       // 16,384 shorts = 32,768 B
    unsigned short* Fh = FG;                          // [128][64] swizzled
    unsigned short* Fl = FG + 128 * 64;
    unsigned short* Gs = FG;                          // [256][64] swizzled
    __shared__ unsigned short Pw[4][16 * PSTRP];      // per-rowgroup P (shared)
    __shared__ float Aly[64];                         // per-row alpha / linv

    const int tid = threadIdx.x;
    const int wid = tid >> 6, lane = tid & 63;
    const int l15 = lane & 15, quad = lane >> 4;

    // theta fragments in registers: wave rows [q0+wid*16, +16), A m = l15
    short8 tHr[8], tLr[8];
    {
        const unsigned short* t1 = thB + (long)(q0 + wid * 16 + l15) * P2;
        const unsigned short* t2 = tlB + (long)(q0 + wid * 16 + l15) * P2;
#pragma unroll
        for (int kt = 0; kt < 8; ++kt) {
            tHr[kt] = *(const short8*)&t1[kt * 32 + quad * 8];
            tLr[kt] = *(const short8*)&t2[kt * 32 + quad * 8];
        }
    }

    float mrun[4], lrun[4];
#pragma unroll
    for (int r = 0; r < 4; ++r) { mrun[r] = -1e30f; lrun[r] = 0.f; }

    // oacc[g*4+pj]: rows g*16+quad*4+r, cols wid*64+pj*16+l15
    floatx4 oacc[16];
#pragma unroll
    for (int p = 0; p < 16; ++p) oacc[p] = (floatx4){0.f, 0.f, 0.f, 0.f};

    // staging: prow = tid>>3 (0..31), slot = tid&7 (16B granule within 64-short row)
    const int prow = tid >> 3, slot = tid & 7;
    short8 pfH[4], pfL[4], pg[8];

    auto loadPhi = [&](int m0, int kc) {
#pragma unroll
        for (int s = 0; s < 4; ++s) {
            const long o = (long)(m0 + prow + s * 32) * P2 + P + kc * 64 + slot * 8;
            pfH[s] = *(const short8*)&thB[o];
            pfL[s] = *(const short8*)&tlB[o];
        }
    };
    auto writePhi = [&]() {
#pragma unroll
        for (int s = 0; s < 4; ++s) {
            *(short8*)&Fh[swz64(prow + s * 32, slot)] = pfH[s];
            *(short8*)&Fl[swz64(prow + s * 32, slot)] = pfL[s];
        }
    };
    auto loadG = [&](int m0, int mc) {
#pragma unroll
        for (int s = 0; s < 8; ++s)
            pg[s] = *(const short8*)&gB[(long)(prow + s * 32) * N + m0 + mc * 64 + slot * 8];
    };
    auto writeG = [&]() {
#pragma unroll
        for (int s = 0; s < 8; ++s)
            *(short8*)&Gs[swz64(prow + s * 32, slot)] = pg[s];
    };

    for (int mt = 0; mt < 4; ++mt) {
        const int m0 = kh * 512 + mt * 128;

        // ---- S phase: 4 chunks of 64 c ----
        floatx4 sacc[8];
#pragma unroll
        for (int j = 0; j < 8; ++j) sacc[j] = (floatx4){0.f, 0.f, 0.f, 0.f};

        loadPhi(m0, 0);
        __syncthreads();            // all waves done reading Gs (prev PV) — alias fence
        writePhi();
        __syncthreads();
#pragma unroll
        for (int kc = 0; kc < 4; ++kc) {
            if (kc < 3) loadPhi(m0, kc + 1);       // prefetch flies over MFMAs
#pragma unroll
            for (int ks = 0; ks < 2; ++ks) {
                const short8 aH = tHr[kc * 2 + ks];
                const short8 aL = tLr[kc * 2 + ks];
#pragma unroll
                for (int j = 0; j < 8; ++j) {
                    const int ro = swz64(j * 16 + l15, ks * 4 + quad);
                    const short8 bh = *(const short8*)&Fh[ro];
                    const short8 bl = *(const short8*)&Fl[ro];
                    sacc[j] = __builtin_amdgcn_mfma_f32_16x16x32_bf16(aH, bh, sacc[j], 0, 0, 0);
                    sacc[j] = __builtin_amdgcn_mfma_f32_16x16x32_bf16(aH, bl, sacc[j], 0, 0, 0);
                    sacc[j] = __builtin_amdgcn_mfma_f32_16x16x32_bf16(aL, bh, sacc[j], 0, 0, 0);
                }
            }
            if (kc < 3) {
                __syncthreads();
                writePhi();                         // vmcnt wait lands here
                __syncthreads();
            }
        }

        // ---- online softmax (registers only; rows = quad*4+r) ----
        float alpha[4];
#pragma unroll
        for (int r = 0; r < 4; ++r) {
            float v = sacc[0][r];
#pragma unroll
            for (int j = 1; j < 8; ++j) v = fmaxf(v, sacc[j][r]);
            v = fmaxf(v, __shfl_xor(v, 1, 64));
            v = fmaxf(v, __shfl_xor(v, 2, 64));
            v = fmaxf(v, __shfl_xor(v, 4, 64));
            v = fmaxf(v, __shfl_xor(v, 8, 64));
            const float mo = mrun[r];
            const float mn = fmaxf(mo, v);
            mrun[r] = mn;
            alpha[r] = __expf(mo - mn);
        }
        float lpart[4] = {0.f, 0.f, 0.f, 0.f};
#pragma unroll
        for (int j = 0; j < 8; ++j)
#pragma unroll
            for (int r = 0; r < 4; ++r) {
                const float p = __expf(sacc[j][r] - mrun[r]);
                Pw[wid][(quad * 4 + r) * PSTRP + j * 16 + l15] = f2bf(p);
                lpart[r] += p;
            }
#pragma unroll
        for (int r = 0; r < 4; ++r) {
            float s = lpart[r];
            s += __shfl_xor(s, 1, 64);
            s += __shfl_xor(s, 2, 64);
            s += __shfl_xor(s, 4, 64);
            s += __shfl_xor(s, 8, 64);
            lrun[r] = lrun[r] * alpha[r] + s;
        }
        if (l15 == 0) {                    // publish row alphas for PV rescale
#pragma unroll
            for (int r = 0; r < 4; ++r) Aly[wid * 16 + quad * 4 + r] = alpha[r];
        }

        // ---- PV phase: square tiling (64q x 64p per wave) ----
        loadG(m0, 0);
        __syncthreads();            // Fh/Fl dead; Pw + Aly now visible to all
        writeG();
        __syncthreads();

        float alr[4][4];
#pragma unroll
        for (int g = 0; g < 4; ++g)
#pragma unroll
            for (int r = 0; r < 4; ++r) alr[g][r] = Aly[g * 16 + quad * 4 + r];
        int noresc = 1;
#pragma unroll
        for (int g = 0; g < 4; ++g)
#pragma unroll
            for (int r = 0; r < 4; ++r) noresc &= (alr[g][r] == 1.f);
        if (!__all(noresc)) {
#pragma unroll
            for (int g = 0; g < 4; ++g)
#pragma unroll
                for (int pj = 0; pj < 4; ++pj)
#pragma unroll
                    for (int r = 0; r < 4; ++r) oacc[g * 4 + pj][r] *= alr[g][r];
        }

#pragma unroll
        for (int mc = 0; mc < 2; ++mc) {
            if (mc == 0) loadG(m0, 1);             // prefetch
#pragma unroll
            for (int kk = 0; kk < 2; ++kk) {
                short8 af[4];
#pragma unroll
                for (int g = 0; g < 4; ++g)
                    af[g] = *(const short8*)&Pw[g][l15 * PSTRP + mc * 64 + kk * 32 + quad * 8];
#pragma unroll
                for (int pj = 0; pj < 4; ++pj) {
                    const short8 bg = *(const short8*)&Gs[swz64(wid * 64 + pj * 16 + l15, kk * 4 + quad)];
#pragma unroll
                    for (int g = 0; g < 4; ++g)
                        oacc[g * 4 + pj] = __builtin_amdgcn_mfma_f32_16x16x32_bf16(af[g], bg, oacc[g * 4 + pj], 0, 0, 0);
                }
            }
            if (mc == 0) {
                __syncthreads();
                writeG();
                __syncthreads();
            }
        }
    }

    // ---- finalize: publish 1/l, scale, write fp32 partial + (m,l) ----
    if (l15 == 0) {
#pragma unroll
        for (int r = 0; r < 4; ++r) Aly[wid * 16 + quad * 4 + r] = 1.0f / lrun[r];
    }
    __syncthreads();
    float liv[4][4];
#pragma unroll
    for (int g = 0; g < 4; ++g)
#pragma unroll
        for (int r = 0; r < 4; ++r) liv[g][r] = Aly[g * 16 + quad * 4 + r];
#pragma unroll
    for (int g = 0; g < 4; ++g)
#pragma unroll
        for (int pj = 0; pj < 4; ++pj)
#pragma unroll
            for (int r = 0; r < 4; ++r) {
                const int row = q0 + g * 16 + quad * 4 + r;
                const int col = wid * 64 + pj * 16 + l15;
                ypB[(long)row * P + col] = oacc[g * 4 + pj][r] * liv[g][r];
            }
    if (l15 == 0) {
#pragma unroll
        for (int r = 0; r < 4; ++r) {
            const int row = q0 + wid * 16 + quad * 4 + r;
            mlB[row] = float2{mrun[r], lrun[r]};
        }
    }
}

// merge the four key-quarter partials: y = sum f_k*y_k, f_k = l_k e^{m_k-m}/Z
__global__ __launch_bounds__(256) void attn_merge(
    const float* __restrict__ yp, const float2* __restrict__ ml,
    unsigned short* __restrict__ ybf)
{
    const long STRIDE = 8L * 2048 * 256;   // per-partial stride (floats)
    const long NROWS  = 8L * 2048;
    const long t = (long)blockIdx.x * 256 + threadIdx.x;
    const long row = t >> 5;
    const int  c0  = ((int)t & 31) * 8;
    const float2 a0 = ml[row];
    const float2 a1 = ml[NROWS + row];
    const float2 a2 = ml[2 * NROWS + row];
    const float2 a3 = ml[3 * NROWS + row];
    const float mx = fmaxf(fmaxf(a0.x, a1.x), fmaxf(a2.x, a3.x));
    const float w0 = a0.y * __expf(a0.x - mx);
    const float w1 = a1.y * __expf(a1.x - mx);
    const float w2 = a2.y * __expf(a2.x - mx);
    const float w3 = a3.y * __expf(a3.x - mx);
    const float inv = 1.0f / (w0 + w1 + w2 + w3);
    const float f0 = w0 * inv, f1 = w1 * inv, f2 = w2 * inv, f3 = w3 * inv;
    const long base = row * 256 + c0;
    const float4 u0 = *(const float4*)&yp[base];
    const float4 u1 = *(const float4*)&yp[base + 4];
    const float4 v0 = *(const float4*)&yp[STRIDE + base];
    const float4 v1 = *(const float4*)&yp[STRIDE + base + 4];
    const float4 p0 = *(const float4*)&yp[2 * STRIDE + base];
    const float4 p1 = *(const float4*)&yp[2 * STRIDE + base + 4];
    const float4 q0 = *(const float4*)&yp[3 * STRIDE + base];
    const float4 q1 = *(const float4*)&yp[3 * STRIDE + base + 4];
    ushort4 o0, o1;
    o0.x = f2bf(f0 * u0.x + f1 * v0.x + f2 * p0.x + f3 * q0.x);
    o0.y = f2bf(f0 * u0.y + f1 * v0.y + f2 * p0.y + f3 * q0.y);
    o0.z = f2bf(f0 * u0.z + f1 * v0.z + f2 * p0.z + f3 * q0.z);
    o0.w = f2bf(f0 * u0.w + f1 * v0.w + f2 * p0.w + f3 * q0.w);
    o1.x = f2bf(f0 * u1.x + f1 * v1.x + f2 * p1.x + f3 * q1.x);
    o1.y = f2bf(f0 * u1.y + f1 * v1.y + f2 * p1.y + f3 * q1.y);
    o1.z = f2bf(f0 * u1.z + f1 * v1.z + f2 * p1.z + f3 * q1.z);
    o1.w = f2bf(f0 * u1.w + f1 * v1.w + f2 * p1.w + f3 * q1.w);
    *(ushort4*)&ybf[base] = o0;
    *(ushort4*)&ybf[base + 4] = o1;
}

// ---------------- BN finalize + apply ----------------
__global__ __launch_bounds__(256) void bn_finalize(
    const float* __restrict__ p1, const float* __restrict__ p2,
    float* __restrict__ mean, float* __restrict__ rstd, float cnt)
{
    const int c = blockIdx.x, t = threadIdx.x;
    __shared__ float rs[256], rq[256];
    rs[t] = p1[(long)c * 256 + t];
    rq[t] = p2[(long)c * 256 + t];
    __syncthreads();
    for (int st = 128; st > 0; st >>= 1) {
        if (t < st) { rs[t] += rs[t + st]; rq[t] += rq[t + st]; }
        __syncthreads();
    }
    if (t == 0) {
        const float m = rs[0] / cnt;
        mean[c] = m;
        rstd[c] = rsqrtf(rq[0] / cnt - m * m + 1e-5f);
    }
}

__global__ __launch_bounds__(256) void bn_apply_bf(
    const unsigned short* __restrict__ z, const float* __restrict__ x,
    const float* __restrict__ mean, const float* __restrict__ rstd,
    const float* __restrict__ gamma, const float* __restrict__ beta,
    float* __restrict__ out, int C, int N)
{
    const long i = ((long)blockIdx.x * 256 + threadIdx.x) * 8;
    const int c = (int)((i / N) % C);
    const float mu = mean[c], rs = rstd[c], ga = gamma[c], be = beta[c];
    const ushort4 z0 = *(const ushort4*)&z[i];
    const ushort4 z1 = *(const ushort4*)&z[i + 4];
    const float4 x0 = *(const float4*)&x[i];
    const float4 x1 = *(const float4*)&x[i + 4];
    float4 o0, o1;
    o0.x = (bf2f(z0.x) - mu) * rs * ga + be + x0.x;
    o0.y = (bf2f(z0.y) - mu) * rs * ga + be + x0.y;
    o0.z = (bf2f(z0.z) - mu) * rs * ga + be + x0.z;
    o0.w = (bf2f(z0.w) - mu) * rs * ga + be + x0.w;
    o1.x = (bf2f(z1.x) - mu) * rs * ga + be + x1.x;
    o1.y = (bf2f(z1.y) - mu) * rs * ga + be + x1.y;
    o1.z = (bf2f(z1.z) - mu) * rs * ga + be + x1.z;
    o1.w = (bf2f(z1.w) - mu) * rs * ga + be + x1.w;
    *(float4*)&out[i] = o0;
    *(float4*)&out[i + 4] = o1;
}

extern "C" void kernel_launch(void* const* d_in, const int* in_sizes, int n_in,
                              void* d_out, int out_size, void* d_ws, size_t ws_size,
                              hipStream_t stream)
{
    const int B = 8, C = 512, N = 2048, P = 256;
    const float* x      = (const float*)d_in[0];
    const float* Wg     = (const float*)d_in[1];
    const float* Wtheta = (const float*)d_in[2];
    const float* Wphi   = (const float*)d_in[3];
    const float* Wz     = (const float*)d_in[4];
    const float* gamma  = (const float*)d_in[5];
    const float* beta   = (const float*)d_in[6];
    float* out = (float*)d_out;

    // ---- workspace layout (float units), same as round 9 ----
    float* ws = (float*)d_ws;
    const long NCle = (long)N * C;            // 1,048,576 per batch (= N*2P)
    const long NP   = (long)N * P;            // 524,288 per batch
    const long R0   = (long)B * NCle;         // 8.39M floats
    unsigned short* xtH   = (unsigned short*)ws;                // B*N*C
    unsigned short* xtL   = xtH + B * NCle;
    unsigned short* zbf   = (unsigned short*)ws;                // aliases xt (dead)
    unsigned short* thphH = (unsigned short*)(ws + R0);         // B*N*2P
    unsigned short* thphL = thphH + B * NCle;                   // B*N*2P
    unsigned short* gbf   = (unsigned short*)(ws + 2 * R0);     // B*P*N
    unsigned short* fbf   = gbf + B * NP;                       // attn partial region
    unsigned short* ybf   = fbf + (long)B * N * N;              // B*N*P
    unsigned short* W2H   = ybf + B * NP;                       // 2P*C
    unsigned short* W2L   = W2H + 2L * P * C;
    unsigned short* WgB   = W2L + 2L * P * C;                   // P*C
    unsigned short* WzB   = WgB + (long)P * C;
    // attn split-K partials: yp[4] exactly fills the dead fbf region
    // (4 * B*N*P floats == B*N*N shorts); ml lives in the dead xtL region
    // (xtL is free after GEMM #4; zbf only spans the xtH half [0, 4.2M floats)).
    float*          yp    = (float*)fbf;                        // [4][B][N][P] fp32
    float2*         ml    = (float2*)(ws + 6L * 1024 * 1024);   // [4][B*N], in xtL
    // BN scratch aliases thph region (dead after fused_attn): [C][256] x2
    float*          bnp1  = ws + R0;
    float*          bnp2  = bnp1 + (long)C * 256;
    float*          mean  = bnp2 + (long)C * 256;
    float*          rstd  = mean + C;

    const long sX = (long)C * N;
    const int  P2 = 2 * P;

    // 1: transpose+split x -> xT hi/lo [B][N][C]
    transpose_split<<<dim3(N / 32, C / 32, B), 256, 0, stream>>>(x, xtH, xtL, C, N);
    // 2: weight preps
    split_w2<<<(2 * P * C + 255) / 256, 256, 0, stream>>>(Wtheta, Wphi, W2H, W2L, P * C);
    cast_bf16<<<P * C / 1024, 256, 0, stream>>>(Wg, WgB);
    cast_bf16<<<P * C / 1024, 256, 0, stream>>>(Wz, WzB);

    // 3: thph [B][N][2P] = xT @ W2^T (split in/out); 128x128, 512 blocks
    mfma_gemm<true, 2, 4, 4><<<dim3(P2 / 128, N / 128, B), 256, 0, stream>>>(
        xtH, xtL, W2H, W2L, thphH, thphL, C, C, C, P2, NCle, 0, NCle, nullptr, nullptr);
    // 4: g [B][P][N] = Wg @ xT^T (plain, bf16 out); 64x128, 512 blocks
    mfma_gemm<false, 1, 2, 4><<<dim3(N / 128, P / 64, B), 256, 0, stream>>>(
        WgB, WgB, xtH, xtH, gbf, gbf, C, C, C, N, 0, NCle, NP, nullptr, nullptr);

    // 5: fused scores+softmax+y, split-K x4 over keys (1024 blocks, 3/CU) + merge
    fused_attn<<<dim3(1024), 256, 0, stream>>>(thphH, thphL, gbf, yp, ml);
    attn_merge<<<dim3(2048), 256, 0, stream>>>(yp, ml, ybf);

    // 6: z [B][C][N] bf16 = Wz @ yT^T, BN partials (thph dead now)
    mfma_gemm<false, 3, 4, 4><<<dim3(N / 128, C / 128, B), 256, 0, stream>>>(
        WzB, WzB, ybf, ybf, zbf, zbf, P, P, P, N, 0, NP, sX, bnp1, bnp2);

    // 7: BN finalize + apply + residual
    bn_finalize<<<C, 256, 0, stream>>>(bnp1, bnp2, mean, rstd, (float)B * N);
    bn_apply_bf<<<(int)((B * sX) / 2048), 256, 0, stream>>>(zbf, x, mean, rstd, gamma, beta, out, C, N);
}

// Round 4
// 281.684 us; speedup vs baseline: 1.4610x; 1.0235x over previous
//
#include <hip/hip_runtime.h>
#include <hip/hip_bf16.h>

// B=8, C=512, N=2048, P=256.
// Round 14: kill the serial [barrier; write; barrier] sandwich in fused_attn.
// R3 lesson: swizzle removed 12x bank conflicts, PV reads halved -> dur FLAT.
// Critical path = per-chunk serialized LDS writes + double barrier drains.
// Change: half-column double-buffering on the SAME [rows][64]+swz64 layout:
//   chunk kc occupies column-half kc&1; per chunk {gload kc+2 || MFMA(kc) ||
//   write(kc+1, other half)} then ONE barrier. Writes overlap MFMAs (disjoint
//   halves under bijective swizzle). Same traffic, same registers, same LDS.
//   PV same treatment (32-key half-chunks). + T5 setprio around MFMA clusters.
// Predicted: fused_attn 111 -> ~90us; MfmaUtil 25.5 -> ~31; VGPR ~128;
// occupancy >25% iff 3 blocks/CU residency is real (diagnostic).

typedef __attribute__((ext_vector_type(8))) short short8;
typedef __attribute__((ext_vector_type(4))) float floatx4;

// ---------------- bf16 helpers ----------------
__device__ __forceinline__ unsigned short f2bf(float v) {
    __hip_bfloat16 h = __float2bfloat16(v);
    return *(unsigned short*)&h;
}
__device__ __forceinline__ float bf2f(unsigned short u) {
    __hip_bfloat16 h;
    *(unsigned short*)&h = u;
    return __bfloat162float(h);
}

// transpose + hi/lo split: X [R][N] fp32 -> Thi/Tlo [N][R] bf16 (batched over z)
__global__ __launch_bounds__(256) void transpose_split(
    const float* __restrict__ X, unsigned short* __restrict__ Thi,
    unsigned short* __restrict__ Tlo, int R, int N)
{
    X   += (long)blockIdx.z * R * N;
    Thi += (long)blockIdx.z * N * R;
    Tlo += (long)blockIdx.z * N * R;
    __shared__ float s[32][33];
    const int tx = threadIdx.x & 31, ty = threadIdx.x >> 5;
    const int n0 = blockIdx.x * 32, r0 = blockIdx.y * 32;
#pragma unroll
    for (int r = 0; r < 4; ++r)
        s[ty + r * 8][tx] = X[(long)(r0 + ty + r * 8) * N + n0 + tx];
    __syncthreads();
#pragma unroll
    for (int r = 0; r < 4; ++r) {
        const int n = ty + r * 8;
        const float v = s[tx][n];
        const unsigned short hi = f2bf(v);
        const unsigned short lo = f2bf(v - bf2f(hi));
        Thi[(long)(n0 + n) * R + r0 + tx] = hi;
        Tlo[(long)(n0 + n) * R + r0 + tx] = lo;
    }
}

// concat [Wth; Wph] rows and hi/lo split: out [2P][C]
__global__ __launch_bounds__(256) void split_w2(
    const float* __restrict__ Wth, const float* __restrict__ Wph,
    unsigned short* __restrict__ Whi, unsigned short* __restrict__ Wlo, int PC)
{
    const int i = blockIdx.x * 256 + threadIdx.x;
    if (i < 2 * PC) {
        const float v = (i < PC) ? Wth[i] : Wph[i - PC];
        const unsigned short hi = f2bf(v);
        Whi[i] = hi;
        Wlo[i] = f2bf(v - bf2f(hi));
    }
}

__global__ __launch_bounds__(256) void cast_bf16(
    const float* __restrict__ X, unsigned short* __restrict__ Y)
{
    const long i = ((long)blockIdx.x * 256 + threadIdx.x) * 4;
    const float4 v = *(const float4*)&X[i];
    ushort4 o;
    o.x = f2bf(v.x); o.y = f2bf(v.y); o.z = f2bf(v.z); o.w = f2bf(v.w);
    *(ushort4*)&Y[i] = o;
}

// ---------------- MFMA GEMM (register-prefetch pipeline, round 7) ----------------
// C[M][N] = A[M][K] * B[N][K]^T, bf16 K-contiguous inputs, fp32 accum.
// OUTMODE: 0 fp32, 1 bf16, 2 hi/lo split bf16, 3 bf16 + BN partials scratch
//          (slot = (bz*gridDim.x+bx)*2 + (wn>>6); [C][256] scratch).
#define BK 32

template <bool SPLIT, int OUTMODE, int FM, int FN>
__global__ __launch_bounds__(256) void mfma_gemm(
    const unsigned short* __restrict__ Ahi, const unsigned short* __restrict__ Alo,
    const unsigned short* __restrict__ Bhi, const unsigned short* __restrict__ Blo,
    void* __restrict__ Cout, void* __restrict__ Cout2,
    int K, int lda, int ldb, int ldc,
    long sA, long sB, long sC,
    float* __restrict__ S1, float* __restrict__ S2)
{
    constexpr int MTM = FM * 32, MTN = FN * 32;
    constexpr int SA = FM / 2, SB = FN / 2;

    Ahi += (long)blockIdx.z * sA;
    Bhi += (long)blockIdx.z * sB;
    if (SPLIT) { Alo += (long)blockIdx.z * sA; Blo += (long)blockIdx.z * sB; }
    float* Cf = (float*)Cout + (long)blockIdx.z * sC;
    unsigned short* Ch = (unsigned short*)Cout + (long)blockIdx.z * sC;
    unsigned short* Cl = (unsigned short*)Cout2 + (long)blockIdx.z * sC;

    __shared__ unsigned short AsH[MTM * BK], BsH[MTN * BK];
    __shared__ unsigned short AsL[SPLIT ? MTM * BK : 8], BsL[SPLIT ? MTN * BK : 8];

    const int tid = threadIdx.x;
    const int wid = tid >> 6, lane = tid & 63;
    const int wm = (wid >> 1) * (FM * 16), wn = (wid & 1) * (FN * 16);
    const int l15 = lane & 15, quad = lane >> 4;
    const int m0 = blockIdx.y * MTM, n0 = blockIdx.x * MTN;

    int arow[SA], acol[SA], brow[SB], bcol[SB];
#pragma unroll
    for (int t = 0; t < SA; ++t) {
        const int gid = t * 256 + tid;
        arow[t] = gid >> 2; acol[t] = (gid & 3) * 8;
    }
#pragma unroll
    for (int t = 0; t < SB; ++t) {
        const int gid = t * 256 + tid;
        brow[t] = gid >> 2; bcol[t] = (gid & 3) * 8;
    }

    short8 pa[SA], pb[SB], paL[SPLIT ? SA : 1], pbL[SPLIT ? SB : 1];

    auto loadTiles = [&](int k0) {
#pragma unroll
        for (int t = 0; t < SA; ++t) {
            const long o = (long)(m0 + arow[t]) * lda + k0 + acol[t];
            pa[t] = *(const short8*)&Ahi[o];
            if (SPLIT) paL[t] = *(const short8*)&Alo[o];
        }
#pragma unroll
        for (int t = 0; t < SB; ++t) {
            const long o = (long)(n0 + brow[t]) * ldb + k0 + bcol[t];
            pb[t] = *(const short8*)&Bhi[o];
            if (SPLIT) pbL[t] = *(const short8*)&Blo[o];
        }
    };
    auto writeTiles = [&]() {
#pragma unroll
        for (int t = 0; t < SA; ++t) {
            *(short8*)&AsH[arow[t] * BK + acol[t]] = pa[t];
            if (SPLIT) *(short8*)&AsL[arow[t] * BK + acol[t]] = paL[t];
        }
#pragma unroll
        for (int t = 0; t < SB; ++t) {
            *(short8*)&BsH[brow[t] * BK + bcol[t]] = pb[t];
            if (SPLIT) *(short8*)&BsL[brow[t] * BK + bcol[t]] = pbL[t];
        }
    };

    floatx4 acc[FM][FN];
#pragma unroll
    for (int i = 0; i < FM; ++i)
#pragma unroll
        for (int j = 0; j < FN; ++j) acc[i][j] = (floatx4){0.f, 0.f, 0.f, 0.f};

    const int iters = K / BK;
    loadTiles(0);
    writeTiles();
    __syncthreads();

    for (int it = 0; it < iters; ++it) {
        if (it + 1 < iters) loadTiles((it + 1) * BK);

        short8 ah[FM], bh[FN], al[SPLIT ? FM : 1], bl[SPLIT ? FN : 1];
#pragma unroll
        for (int i = 0; i < FM; ++i) {
            ah[i] = *(const short8*)&AsH[(wm + i * 16 + l15) * BK + quad * 8];
            if (SPLIT) al[i] = *(const short8*)&AsL[(wm + i * 16 + l15) * BK + quad * 8];
        }
#pragma unroll
        for (int j = 0; j < FN; ++j) {
            bh[j] = *(const short8*)&BsH[(wn + j * 16 + l15) * BK + quad * 8];
            if (SPLIT) bl[j] = *(const short8*)&BsL[(wn + j * 16 + l15) * BK + quad * 8];
        }
#pragma unroll
        for (int i = 0; i < FM; ++i)
#pragma unroll
            for (int j = 0; j < FN; ++j) {
                acc[i][j] = __builtin_amdgcn_mfma_f32_16x16x32_bf16(ah[i], bh[j], acc[i][j], 0, 0, 0);
                if (SPLIT) {
                    acc[i][j] = __builtin_amdgcn_mfma_f32_16x16x32_bf16(ah[i], bl[j], acc[i][j], 0, 0, 0);
                    acc[i][j] = __builtin_amdgcn_mfma_f32_16x16x32_bf16(al[i], bh[j], acc[i][j], 0, 0, 0);
                }
            }

        if (it + 1 < iters) {
            __syncthreads();
            writeTiles();
            __syncthreads();
        }
    }

#pragma unroll
    for (int i = 0; i < FM; ++i)
#pragma unroll
        for (int j = 0; j < FN; ++j) {
            const int m = m0 + wm + i * 16 + quad * 4;
            const int n = n0 + wn + j * 16 + l15;
#pragma unroll
            for (int r = 0; r < 4; ++r) {
                const float v = acc[i][j][r];
                const long idx = (long)(m + r) * ldc + n;
                if (OUTMODE == 0) {
                    Cf[idx] = v;
                } else if (OUTMODE == 1 || OUTMODE == 3) {
                    Ch[idx] = f2bf(v);
                } else {
                    const unsigned short hi = f2bf(v);
                    Ch[idx] = hi;
                    Cl[idx] = f2bf(v - bf2f(hi));
                }
            }
        }

    if (OUTMODE == 3) {
        const int slot = (blockIdx.z * gridDim.x + blockIdx.x) * 2 + (wn >> 6);
#pragma unroll
        for (int i = 0; i < FM; ++i)
#pragma unroll
            for (int r = 0; r < 4; ++r) {
                float s = 0.f, q = 0.f;
#pragma unroll
                for (int j = 0; j < FN; ++j) {
                    const float v = acc[i][j][r];
                    s += v; q += v * v;
                }
#pragma unroll
                for (int msk = 1; msk < 16; msk <<= 1) {
                    s += __shfl_xor(s, msk, 64);
                    q += __shfl_xor(q, msk, 64);
                }
                if (l15 == 0) {
                    const int row = m0 + wm + i * 16 + quad * 4 + r;
                    S1[(long)row * 256 + slot] = s;
                    S2[(long)row * 256 + slot] = q;
                }
            }
    }
}

// ---------------- fused scores+softmax+y v5 (half-column dbuf, 1 barrier/chunk) ----
// 1024 blocks (b = id&7, kh = (id>>3)&3, qt = id>>5), 4 waves.
// S phase: 8 chunks of 32 c; chunk kc lives in column-half kc&1 of the
//   [128][64]+swz64 phi tile; per chunk {gload kc+2 | MFMA kc | write kc+1}
//   then ONE barrier (write targets the half not being read).
// PV phase: square tiling (64q x 64p/wave), 4 chunks of 32 keys, same dbuf.
// LDS: FG 32,768B (aliased phi/G) + Pw 17,408B + Aly 256B = 50,432B.
#define PSTRP 136   // P LDS row stride (128 keys + 8 pad)

// swizzled short-offset into a [rows][64-short] tile: 16B slot ^= row&7
__device__ __forceinline__ int swz64(int row, int slot) {
    return (row << 6) + (((slot ^ row) & 7) << 3);
}

__global__ __launch_bounds__(256, 2) void fused_attn(
    const unsigned short* __restrict__ thphH,
    const unsigned short* __restrict__ thphL,
    const unsigned short* __restrict__ gbf,
    float* __restrict__ yp,       // [4][B][N][P] fp32 partials (self-normalized)
    float2* __restrict__ ml)      // [4][B*N] {m, l}
{
    const int N = 2048, P = 256, P2 = 512;
    const int id = blockIdx.x;
    const int b  = id & 7;            // XCD-locality heuristic
    const int kh = (id >> 3) & 3;     // key quarter
    const int qt = id >> 5;           // 0..31
    const int q0 = qt * 64;

    const unsigned short* thB = thphH + (long)b * N * P2;
    const unsigned short* tlB = thphL + (long)b * N * P2;
    const unsigned short* gB  = gbf   + (long)b * P * N;
    float*  ypB = yp + (long)kh * (8L * N * P) + (long)b * N * P;
    float2* mlB = ml + (long)kh * (8L * N) + (long)b * N;

    // phi hi/lo and G share the same LDS (disjoint phases / halves, fenced)
    __shared__ unsigned short FG[2 * 128 * 64];       // 16,384 shorts = 32,768 B
    unsigned short* Fh = FG;                          // [128][64] swizzled
    unsigned short* Fl = FG + 128 * 64;
    unsigned short* Gs = FG;                          // [256][64] swizzled
    __shared__ unsigned short Pw[4][16 * PSTRP];      // per-rowgroup P (shared)
    __shared__ float Aly[64];                         // per-row alpha / linv

    const int tid = threadIdx.x;
    const int wid = tid >> 6, lane = tid & 63;
    const int l15 = lane & 15, quad = lane >> 4;

    // theta fragments in registers: wave rows [q0+wid*16, +16), A m = l15
    short8 tHr[8], tLr[8];
    {
        const unsigned short* t1 = thB + (long)(q0 + wid * 16 + l15) * P2;
        const unsigned short* t2 = tlB + (long)(q0 + wid * 16 + l15) * P2;
#pragma unroll
        for (int kt = 0; kt < 8; ++kt) {
            tHr[kt] = *(const short8*)&t1[kt * 32 + quad * 8];
            tLr[kt] = *(const short8*)&t2[kt * 32 + quad * 8];
        }
    }

    float mrun[4], lrun[4];
#pragma unroll
    for (int r = 0; r < 4; ++r) { mrun[r] = -1e30f; lrun[r] = 0.f; }

    // oacc[g*4+pj]: rows g*16+quad*4+r, cols wid*64+pj*16+l15
    floatx4 oacc[16];
#pragma unroll
    for (int p = 0; p < 16; ++p) oacc[p] = (floatx4){0.f, 0.f, 0.f, 0.f};

    // staging: prow4 = tid>>2 (0..63), lslot = tid&3 (16B granule in 32-short half)
    const int prow4 = tid >> 2, lslot = tid & 3;
    short8 pfH[2][2], pfL[2][2];   // [set][s], set = chunk&1 (static under unroll)
    short8 pg[2][4];

    for (int mt = 0; mt < 4; ++mt) {
        const int m0 = kh * 512 + mt * 128;

        // ---- S phase: 8 chunks of 32 c, half-column dbuf ----
        floatx4 sacc[8];
#pragma unroll
        for (int j = 0; j < 8; ++j) sacc[j] = (floatx4){0.f, 0.f, 0.f, 0.f};

        // prologue: chunk0 -> half0 (prev-tile PV half0 reads fenced at its mc2
        // barrier; prev mc3 read half1 — disjoint), prefetch chunk1.
#pragma unroll
        for (int s = 0; s < 2; ++s) {
            const long o = (long)(m0 + s * 64 + prow4) * P2 + P + 0 * 32 + lslot * 8;
            pfH[0][s] = *(const short8*)&thB[o];
            pfL[0][s] = *(const short8*)&tlB[o];
        }
#pragma unroll
        for (int s = 0; s < 2; ++s) {
            const int row = s * 64 + prow4;
            *(short8*)&Fh[swz64(row, lslot)] = pfH[0][s];
            *(short8*)&Fl[swz64(row, lslot)] = pfL[0][s];
        }
#pragma unroll
        for (int s = 0; s < 2; ++s) {
            const long o = (long)(m0 + s * 64 + prow4) * P2 + P + 1 * 32 + lslot * 8;
            pfH[1][s] = *(const short8*)&thB[o];
            pfL[1][s] = *(const short8*)&tlB[o];
        }
        __syncthreads();

#pragma unroll
        for (int kc = 0; kc < 8; ++kc) {
            if (kc < 6) {                        // prefetch chunk kc+2 into set kc&1
#pragma unroll
                for (int s = 0; s < 2; ++s) {
                    const long o = (long)(m0 + s * 64 + prow4) * P2 + P + (kc + 2) * 32 + lslot * 8;
                    pfH[kc & 1][s] = *(const short8*)&thB[o];
                    pfL[kc & 1][s] = *(const short8*)&tlB[o];
                }
            }
            const short8 aH = tHr[kc];
            const short8 aL = tLr[kc];
            const int half = (kc & 1) * 4;
            __builtin_amdgcn_s_setprio(1);
#pragma unroll
            for (int j = 0; j < 8; ++j) {
                const int ro = swz64(j * 16 + l15, half + quad);
                const short8 bh = *(const short8*)&Fh[ro];
                const short8 bl = *(const short8*)&Fl[ro];
                sacc[j] = __builtin_amdgcn_mfma_f32_16x16x32_bf16(aH, bh, sacc[j], 0, 0, 0);
                sacc[j] = __builtin_amdgcn_mfma_f32_16x16x32_bf16(aH, bl, sacc[j], 0, 0, 0);
                sacc[j] = __builtin_amdgcn_mfma_f32_16x16x32_bf16(aL, bh, sacc[j], 0, 0, 0);
            }
            __builtin_amdgcn_s_setprio(0);
            if (kc < 7) {                        // write chunk kc+1 into other half
                const int wh = ((kc + 1) & 1) * 4;
#pragma unroll
                for (int s = 0; s < 2; ++s) {
                    const int row = s * 64 + prow4;
                    *(short8*)&Fh[swz64(row, wh + lslot)] = pfH[(kc + 1) & 1][s];
                    *(short8*)&Fl[swz64(row, wh + lslot)] = pfL[(kc + 1) & 1][s];
                }
            }
            __syncthreads();
        }

        // ---- online softmax (registers only; rows = quad*4+r) ----
        float alpha[4];
#pragma unroll
        for (int r = 0; r < 4; ++r) {
            float v = sacc[0][r];
#pragma unroll
            for (int j = 1; j < 8; ++j) v = fmaxf(v, sacc[j][r]);
            v = fmaxf(v, __shfl_xor(v, 1, 64));
            v = fmaxf(v, __shfl_xor(v, 2, 64));
            v = fmaxf(v, __shfl_xor(v, 4, 64));
            v = fmaxf(v, __shfl_xor(v, 8, 64));
            const float mo = mrun[r];
            const float mn = fmaxf(mo, v);
            mrun[r] = mn;
            alpha[r] = __expf(mo - mn);
        }
        float lpart[4] = {0.f, 0.f, 0.f, 0.f};
#pragma unroll
        for (int j = 0; j < 8; ++j)
#pragma unroll
            for (int r = 0; r < 4; ++r) {
                const float p = __expf(sacc[j][r] - mrun[r]);
                Pw[wid][(quad * 4 + r) * PSTRP + j * 16 + l15] = f2bf(p);
                lpart[r] += p;
            }
#pragma unroll
        for (int r = 0; r < 4; ++r) {
            float s = lpart[r];
            s += __shfl_xor(s, 1, 64);
            s += __shfl_xor(s, 2, 64);
            s += __shfl_xor(s, 4, 64);
            s += __shfl_xor(s, 8, 64);
            lrun[r] = lrun[r] * alpha[r] + s;
        }
        if (l15 == 0) {                    // publish row alphas for PV rescale
#pragma unroll
            for (int r = 0; r < 4; ++r) Aly[wid * 16 + quad * 4 + r] = alpha[r];
        }

        // ---- PV phase: square tiling, 4 chunks of 32 keys, half dbuf ----
        // G chunk0 -> half0 (S kc6 half0 reads fenced at kc6 barrier; kc7 read half1)
#pragma unroll
        for (int s = 0; s < 4; ++s)
            pg[0][s] = *(const short8*)&gB[(long)(s * 64 + prow4) * N + m0 + 0 * 32 + lslot * 8];
#pragma unroll
        for (int s = 0; s < 4; ++s)
            *(short8*)&Gs[swz64(s * 64 + prow4, lslot)] = pg[0][s];
#pragma unroll
        for (int s = 0; s < 4; ++s)
            pg[1][s] = *(const short8*)&gB[(long)(s * 64 + prow4) * N + m0 + 1 * 32 + lslot * 8];
        __syncthreads();   // G0 + Pw + Aly visible

        float alr[4][4];
#pragma unroll
        for (int g = 0; g < 4; ++g)
#pragma unroll
            for (int r = 0; r < 4; ++r) alr[g][r] = Aly[g * 16 + quad * 4 + r];
        int noresc = 1;
#pragma unroll
        for (int g = 0; g < 4; ++g)
#pragma unroll
            for (int r = 0; r < 4; ++r) noresc &= (alr[g][r] == 1.f);
        if (!__all(noresc)) {
#pragma unroll
            for (int g = 0; g < 4; ++g)
#pragma unroll
                for (int pj = 0; pj < 4; ++pj)
#pragma unroll
                    for (int r = 0; r < 4; ++r) oacc[g * 4 + pj][r] *= alr[g][r];
        }

#pragma unroll
        for (int mc = 0; mc < 4; ++mc) {
            if (mc < 2) {                        // prefetch chunk mc+2 into set mc&1
#pragma unroll
                for (int s = 0; s < 4; ++s)
                    pg[mc & 1][s] = *(const short8*)&gB[(long)(s * 64 + prow4) * N + m0 + (mc + 2) * 32 + lslot * 8];
            }
            const int half = (mc & 1) * 4;
            short8 af[4];
#pragma unroll
            for (int g = 0; g < 4; ++g)
                af[g] = *(const short8*)&Pw[g][l15 * PSTRP + mc * 32 + quad * 8];
            __builtin_amdgcn_s_setprio(1);
#pragma unroll
            for (int pj = 0; pj < 4; ++pj) {
                const short8 bg = *(const short8*)&Gs[swz64(wid * 64 + pj * 16 + l15, half + quad)];
#pragma unroll
                for (int g = 0; g < 4; ++g)
                    oacc[g * 4 + pj] = __builtin_amdgcn_mfma_f32_16x16x32_bf16(af[g], bg, oacc[g * 4 + pj], 0, 0, 0);
            }
            __builtin_amdgcn_s_setprio(0);
            if (mc < 3) {                        // write chunk mc+1 into other half
                const int wh = ((mc + 1) & 1) * 4;
#pragma unroll
                for (int s = 0; s < 4; ++s)
                    *(short8*)&Gs[swz64(s * 64 + prow4, wh + lslot)] = pg[(mc + 1) & 1][s];
                __syncthreads();
            }
        }
    }

    // ---- finalize: publish 1/l, scale, write fp32 partial + (m,l) ----
    if (l15 == 0) {
#pragma unroll
        for (int r = 0; r < 4; ++r) Aly[wid * 16 + quad * 4 + r] = 1.0f / lrun[r];
    }
    __syncthreads();
    float liv[4][4];
#pragma unroll
    for (int g = 0; g < 4; ++g)
#pragma unroll
        for (int r = 0; r < 4; ++r) liv[g][r] = Aly[g * 16 + quad * 4 + r];
#pragma unroll
    for (int g = 0; g < 4; ++g)
#pragma unroll
        for (int pj = 0; pj < 4; ++pj)
#pragma unroll
            for (int r = 0; r < 4; ++r) {
                const int row = q0 + g * 16 + quad * 4 + r;
                const int col = wid * 64 + pj * 16 + l15;
                ypB[(long)row * P + col] = oacc[g * 4 + pj][r] * liv[g][r];
            }
    if (l15 == 0) {
#pragma unroll
        for (int r = 0; r < 4; ++r) {
            const int row = q0 + wid * 16 + quad * 4 + r;
            mlB[row] = float2{mrun[r], lrun[r]};
        }
    }
}

// merge the four key-quarter partials: y = sum f_k*y_k, f_k = l_k e^{m_k-m}/Z
__global__ __launch_bounds__(256) void attn_merge(
    const float* __restrict__ yp, const float2* __restrict__ ml,
    unsigned short* __restrict__ ybf)
{
    const long STRIDE = 8L * 2048 * 256;   // per-partial stride (floats)
    const long NROWS  = 8L * 2048;
    const long t = (long)blockIdx.x * 256 + threadIdx.x;
    const long row = t >> 5;
    const int  c0  = ((int)t & 31) * 8;
    const float2 a0 = ml[row];
    const float2 a1 = ml[NROWS + row];
    const float2 a2 = ml[2 * NROWS + row];
    const float2 a3 = ml[3 * NROWS + row];
    const float mx = fmaxf(fmaxf(a0.x, a1.x), fmaxf(a2.x, a3.x));
    const float w0 = a0.y * __expf(a0.x - mx);
    const float w1 = a1.y * __expf(a1.x - mx);
    const float w2 = a2.y * __expf(a2.x - mx);
    const float w3 = a3.y * __expf(a3.x - mx);
    const float inv = 1.0f / (w0 + w1 + w2 + w3);
    const float f0 = w0 * inv, f1 = w1 * inv, f2 = w2 * inv, f3 = w3 * inv;
    const long base = row * 256 + c0;
    const float4 u0 = *(const float4*)&yp[base];
    const float4 u1 = *(const float4*)&yp[base + 4];
    const float4 v0 = *(const float4*)&yp[STRIDE + base];
    const float4 v1 = *(const float4*)&yp[STRIDE + base + 4];
    const float4 p0 = *(const float4*)&yp[2 * STRIDE + base];
    const float4 p1 = *(const float4*)&yp[2 * STRIDE + base + 4];
    const float4 q0 = *(const float4*)&yp[3 * STRIDE + base];
    const float4 q1 = *(const float4*)&yp[3 * STRIDE + base + 4];
    ushort4 o0, o1;
    o0.x = f2bf(f0 * u0.x + f1 * v0.x + f2 * p0.x + f3 * q0.x);
    o0.y = f2bf(f0 * u0.y + f1 * v0.y + f2 * p0.y + f3 * q0.y);
    o0.z = f2bf(f0 * u0.z + f1 * v0.z + f2 * p0.z + f3 * q0.z);
    o0.w = f2bf(f0 * u0.w + f1 * v0.w + f2 * p0.w + f3 * q0.w);
    o1.x = f2bf(f0 * u1.x + f1 * v1.x + f2 * p1.x + f3 * q1.x);
    o1.y = f2bf(f0 * u1.y + f1 * v1.y + f2 * p1.y + f3 * q1.y);
    o1.z = f2bf(f0 * u1.z + f1 * v1.z + f2 * p1.z + f3 * q1.z);
    o1.w = f2bf(f0 * u1.w + f1 * v1.w + f2 * p1.w + f3 * q1.w);
    *(ushort4*)&ybf[base] = o0;
    *(ushort4*)&ybf[base + 4] = o1;
}

// ---------------- BN finalize + apply ----------------
__global__ __launch_bounds__(256) void bn_finalize(
    const float* __restrict__ p1, const float* __restrict__ p2,
    float* __restrict__ mean, float* __restrict__ rstd, float cnt)
{
    const int c = blockIdx.x, t = threadIdx.x;
    __shared__ float rs[256], rq[256];
    rs[t] = p1[(long)c * 256 + t];
    rq[t] = p2[(long)c * 256 + t];
    __syncthreads();
    for (int st = 128; st > 0; st >>= 1) {
        if (t < st) { rs[t] += rs[t + st]; rq[t] += rq[t + st]; }
        __syncthreads();
    }
    if (t == 0) {
        const float m = rs[0] / cnt;
        mean[c] = m;
        rstd[c] = rsqrtf(rq[0] / cnt - m * m + 1e-5f);
    }
}

__global__ __launch_bounds__(256) void bn_apply_bf(
    const unsigned short* __restrict__ z, const float* __restrict__ x,
    const float* __restrict__ mean, const float* __restrict__ rstd,
    const float* __restrict__ gamma, const float* __restrict__ beta,
    float* __restrict__ out, int C, int N)
{
    const long i = ((long)blockIdx.x * 256 + threadIdx.x) * 8;
    const int c = (int)((i / N) % C);
    const float mu = mean[c], rs = rstd[c], ga = gamma[c], be = beta[c];
    const ushort4 z0 = *(const ushort4*)&z[i];
    const ushort4 z1 = *(const ushort4*)&z[i + 4];
    const float4 x0 = *(const float4*)&x[i];
    const float4 x1 = *(const float4*)&x[i + 4];
    float4 o0, o1;
    o0.x = (bf2f(z0.x) - mu) * rs * ga + be + x0.x;
    o0.y = (bf2f(z0.y) - mu) * rs * ga + be + x0.y;
    o0.z = (bf2f(z0.z) - mu) * rs * ga + be + x0.z;
    o0.w = (bf2f(z0.w) - mu) * rs * ga + be + x0.w;
    o1.x = (bf2f(z1.x) - mu) * rs * ga + be + x1.x;
    o1.y = (bf2f(z1.y) - mu) * rs * ga + be + x1.y;
    o1.z = (bf2f(z1.z) - mu) * rs * ga + be + x1.z;
    o1.w = (bf2f(z1.w) - mu) * rs * ga + be + x1.w;
    *(float4*)&out[i] = o0;
    *(float4*)&out[i + 4] = o1;
}

extern "C" void kernel_launch(void* const* d_in, const int* in_sizes, int n_in,
                              void* d_out, int out_size, void* d_ws, size_t ws_size,
                              hipStream_t stream)
{
    const int B = 8, C = 512, N = 2048, P = 256;
    const float* x      = (const float*)d_in[0];
    const float* Wg     = (const float*)d_in[1];
    const float* Wtheta = (const float*)d_in[2];
    const float* Wphi   = (const float*)d_in[3];
    const float* Wz     = (const float*)d_in[4];
    const float* gamma  = (const float*)d_in[5];
    const float* beta   = (const float*)d_in[6];
    float* out = (float*)d_out;

    // ---- workspace layout (float units), same as round 9 ----
    float* ws = (float*)d_ws;
    const long NCle = (long)N * C;            // 1,048,576 per batch (= N*2P)
    const long NP   = (long)N * P;            // 524,288 per batch
    const long R0   = (long)B * NCle;         // 8.39M floats
    unsigned short* xtH   = (unsigned short*)ws;                // B*N*C
    unsigned short* xtL   = xtH + B * NCle;
    unsigned short* zbf   = (unsigned short*)ws;                // aliases xt (dead)
    unsigned short* thphH = (unsigned short*)(ws + R0);         // B*N*2P
    unsigned short* thphL = thphH + B * NCle;                   // B*N*2P
    unsigned short* gbf   = (unsigned short*)(ws + 2 * R0);     // B*P*N
    unsigned short* fbf   = gbf + B * NP;                       // attn partial region
    unsigned short* ybf   = fbf + (long)B * N * N;              // B*N*P
    unsigned short* W2H   = ybf + B * NP;                       // 2P*C
    unsigned short* W2L   = W2H + 2L * P * C;
    unsigned short* WgB   = W2L + 2L * P * C;                   // P*C
    unsigned short* WzB   = WgB + (long)P * C;
    // attn split-K partials: yp[4] exactly fills the dead fbf region
    // (4 * B*N*P floats == B*N*N shorts); ml lives in the dead xtL region
    // (xtL is free after GEMM #4; zbf only spans the xtH half [0, 4.2M floats)).
    float*          yp    = (float*)fbf;                        // [4][B][N][P] fp32
    float2*         ml    = (float2*)(ws + 6L * 1024 * 1024);   // [4][B*N], in xtL
    // BN scratch aliases thph region (dead after fused_attn): [C][256] x2
    float*          bnp1  = ws + R0;
    float*          bnp2  = bnp1 + (long)C * 256;
    float*          mean  = bnp2 + (long)C * 256;
    float*          rstd  = mean + C;

    const long sX = (long)C * N;
    const int  P2 = 2 * P;

    // 1: transpose+split x -> xT hi/lo [B][N][C]
    transpose_split<<<dim3(N / 32, C / 32, B), 256, 0, stream>>>(x, xtH, xtL, C, N);
    // 2: weight preps
    split_w2<<<(2 * P * C + 255) / 256, 256, 0, stream>>>(Wtheta, Wphi, W2H, W2L, P * C);
    cast_bf16<<<P * C / 1024, 256, 0, stream>>>(Wg, WgB);
    cast_bf16<<<P * C / 1024, 256, 0, stream>>>(Wz, WzB);

    // 3: thph [B][N][2P] = xT @ W2^T (split in/out); 128x128, 512 blocks
    mfma_gemm<true, 2, 4, 4><<<dim3(P2 / 128, N / 128, B), 256, 0, stream>>>(
        xtH, xtL, W2H, W2L, thphH, thphL, C, C, C, P2, NCle, 0, NCle, nullptr, nullptr);
    // 4: g [B][P][N] = Wg @ xT^T (plain, bf16 out); 64x128, 512 blocks
    mfma_gemm<false, 1, 2, 4><<<dim3(N / 128, P / 64, B), 256, 0, stream>>>(
        WgB, WgB, xtH, xtH, gbf, gbf, C, C, C, N, 0, NCle, NP, nullptr, nullptr);

    // 5: fused scores+softmax+y, split-K x4 over keys (1024 blocks) + merge
    fused_attn<<<dim3(1024), 256, 0, stream>>>(thphH, thphL, gbf, yp, ml);
    attn_merge<<<dim3(2048), 256, 0, stream>>>(yp, ml, ybf);

    // 6: z [B][C][N] bf16 = Wz @ yT^T, BN partials (thph dead now)
    mfma_gemm<false, 3, 4, 4><<<dim3(N / 128, C / 128, B), 256, 0, stream>>>(
        WzB, WzB, ybf, ybf, zbf, zbf, P, P, P, N, 0, NP, sX, bnp1, bnp2);

    // 7: BN finalize + apply + residual
    bn_finalize<<<C, 256, 0, stream>>>(bnp1, bnp2, mean, rstd, (float)B * N);
    bn_apply_bf<<<(int)((B * sX) / 2048), 256, 0, stream>>>(zbf, x, mean, rstd, gamma, beta, out, C, N);
}

// Round 5
// 266.864 us; speedup vs baseline: 1.5422x; 1.0555x over previous
//
#include <hip/hip_runtime.h>
#include <hip/hip_bf16.h>

// B=8, C=512, N=2048, P=256.
// Round 15: system round.
//   - mfma_gemm rewritten: async global_load_lds (width 16) + double-buffered
//     LDS + ONE barrier per K-step (m97 ladder pattern, Common-mistake #1).
//     Staging map already wave-linear (dest = gid*16B); global src per-lane.
//   - fused_attn: R4 body unchanged, kh 4->2 (occupancy pinned at 2 blocks/CU
//     regardless, so split-4 was pure partial-traffic overhead). Grid 512,
//     8 key-tiles/block; yp [2] fp32 partials; 2-way merge.
// Predicted: GEMM3 ~50->33us, GEMM4 14->10, GEMM6 18->13, merge 12->6,
// fused ~105 (WRITE 66->33.5MB). Total 281.7 -> ~248us.

typedef __attribute__((ext_vector_type(8))) short short8;
typedef __attribute__((ext_vector_type(4))) float floatx4;

// ---------------- bf16 helpers ----------------
__device__ __forceinline__ unsigned short f2bf(float v) {
    __hip_bfloat16 h = __float2bfloat16(v);
    return *(unsigned short*)&h;
}
__device__ __forceinline__ float bf2f(unsigned short u) {
    __hip_bfloat16 h;
    *(unsigned short*)&h = u;
    return __bfloat162float(h);
}

// async global->LDS 16B per lane (dest must be wave-linear: base + lane*16)
__device__ __forceinline__ void gl16(const unsigned short* g, unsigned short* l) {
    __builtin_amdgcn_global_load_lds(
        (const __attribute__((address_space(1))) unsigned int*)g,
        (__attribute__((address_space(3))) unsigned int*)l, 16, 0, 0);
}

// transpose + hi/lo split: X [R][N] fp32 -> Thi/Tlo [N][R] bf16 (batched over z)
__global__ __launch_bounds__(256) void transpose_split(
    const float* __restrict__ X, unsigned short* __restrict__ Thi,
    unsigned short* __restrict__ Tlo, int R, int N)
{
    X   += (long)blockIdx.z * R * N;
    Thi += (long)blockIdx.z * N * R;
    Tlo += (long)blockIdx.z * N * R;
    __shared__ float s[32][33];
    const int tx = threadIdx.x & 31, ty = threadIdx.x >> 5;
    const int n0 = blockIdx.x * 32, r0 = blockIdx.y * 32;
#pragma unroll
    for (int r = 0; r < 4; ++r)
        s[ty + r * 8][tx] = X[(long)(r0 + ty + r * 8) * N + n0 + tx];
    __syncthreads();
#pragma unroll
    for (int r = 0; r < 4; ++r) {
        const int n = ty + r * 8;
        const float v = s[tx][n];
        const unsigned short hi = f2bf(v);
        const unsigned short lo = f2bf(v - bf2f(hi));
        Thi[(long)(n0 + n) * R + r0 + tx] = hi;
        Tlo[(long)(n0 + n) * R + r0 + tx] = lo;
    }
}

// concat [Wth; Wph] rows and hi/lo split: out [2P][C]
__global__ __launch_bounds__(256) void split_w2(
    const float* __restrict__ Wth, const float* __restrict__ Wph,
    unsigned short* __restrict__ Whi, unsigned short* __restrict__ Wlo, int PC)
{
    const int i = blockIdx.x * 256 + threadIdx.x;
    if (i < 2 * PC) {
        const float v = (i < PC) ? Wth[i] : Wph[i - PC];
        const unsigned short hi = f2bf(v);
        Whi[i] = hi;
        Wlo[i] = f2bf(v - bf2f(hi));
    }
}

__global__ __launch_bounds__(256) void cast_bf16(
    const float* __restrict__ X, unsigned short* __restrict__ Y)
{
    const long i = ((long)blockIdx.x * 256 + threadIdx.x) * 4;
    const float4 v = *(const float4*)&X[i];
    ushort4 o;
    o.x = f2bf(v.x); o.y = f2bf(v.y); o.z = f2bf(v.z); o.w = f2bf(v.w);
    *(ushort4*)&Y[i] = o;
}

// ---------------- MFMA GEMM (async global_load_lds, double-buffered) ----------
// C[M][N] = A[M][K] * B[N][K]^T, bf16 K-contiguous inputs, fp32 accum.
// OUTMODE: 0 fp32, 1 bf16, 2 hi/lo split bf16, 3 bf16 + BN partials scratch
//          (slot = (bz*gridDim.x+bx)*2 + (wn>>6); [C][256] scratch).
#define BK 32

template <bool SPLIT, int OUTMODE, int FM, int FN>
__global__ __launch_bounds__(256) void mfma_gemm(
    const unsigned short* __restrict__ Ahi, const unsigned short* __restrict__ Alo,
    const unsigned short* __restrict__ Bhi, const unsigned short* __restrict__ Blo,
    void* __restrict__ Cout, void* __restrict__ Cout2,
    int K, int lda, int ldb, int ldc,
    long sA, long sB, long sC,
    float* __restrict__ S1, float* __restrict__ S2)
{
    constexpr int MTM = FM * 32, MTN = FN * 32;
    constexpr int SA = FM / 2, SB = FN / 2;
    constexpr int ASZ = MTM * BK, BSZ = MTN * BK;

    Ahi += (long)blockIdx.z * sA;
    Bhi += (long)blockIdx.z * sB;
    if (SPLIT) { Alo += (long)blockIdx.z * sA; Blo += (long)blockIdx.z * sB; }
    float* Cf = (float*)Cout + (long)blockIdx.z * sC;
    unsigned short* Ch = (unsigned short*)Cout + (long)blockIdx.z * sC;
    unsigned short* Cl = (unsigned short*)Cout2 + (long)blockIdx.z * sC;

    __shared__ unsigned short AsH[2 * ASZ], BsH[2 * BSZ];
    __shared__ unsigned short AsL[SPLIT ? 2 * ASZ : 8], BsL[SPLIT ? 2 * BSZ : 8];

    const int tid = threadIdx.x;
    const int wid = tid >> 6, lane = tid & 63;
    const int wm = (wid >> 1) * (FM * 16), wn = (wid & 1) * (FN * 16);
    const int l15 = lane & 15, quad = lane >> 4;
    const int m0 = blockIdx.y * MTM, n0 = blockIdx.x * MTN;

    // staging map: gid = t*256+tid -> row = gid>>2, col = (gid&3)*8.
    // LDS dest offset = gid*8 shorts (wave-linear: lane-contiguous 16B) ✓
    int arow[SA], acol[SA], brow[SB], bcol[SB];
#pragma unroll
    for (int t = 0; t < SA; ++t) {
        const int gid = t * 256 + tid;
        arow[t] = gid >> 2; acol[t] = (gid & 3) * 8;
    }
#pragma unroll
    for (int t = 0; t < SB; ++t) {
        const int gid = t * 256 + tid;
        brow[t] = gid >> 2; bcol[t] = (gid & 3) * 8;
    }

    auto stage = [&](int k0, int buf) {
#pragma unroll
        for (int t = 0; t < SA; ++t) {
            const long o = (long)(m0 + arow[t]) * lda + k0 + acol[t];
            const int d = buf * ASZ + (t * 256 + tid) * 8;
            gl16(&Ahi[o], &AsH[d]);
            if (SPLIT) gl16(&Alo[o], &AsL[d]);
        }
#pragma unroll
        for (int t = 0; t < SB; ++t) {
            const long o = (long)(n0 + brow[t]) * ldb + k0 + bcol[t];
            const int d = buf * BSZ + (t * 256 + tid) * 8;
            gl16(&Bhi[o], &BsH[d]);
            if (SPLIT) gl16(&Blo[o], &BsL[d]);
        }
    };

    floatx4 acc[FM][FN];
#pragma unroll
    for (int i = 0; i < FM; ++i)
#pragma unroll
        for (int j = 0; j < FN; ++j) acc[i][j] = (floatx4){0.f, 0.f, 0.f, 0.f};

    const int iters = K / BK;
    stage(0, 0);
    __syncthreads();          // compiler drains vmcnt(0) before barrier

    for (int it = 0; it < iters; ++it) {
        const int cur = it & 1;
        if (it + 1 < iters) stage((it + 1) * BK, cur ^ 1);   // async, flies over MFMAs

        short8 ah[FM], bh[FN], al[SPLIT ? FM : 1], bl[SPLIT ? FN : 1];
#pragma unroll
        for (int i = 0; i < FM; ++i) {
            ah[i] = *(const short8*)&AsH[cur * ASZ + (wm + i * 16 + l15) * BK + quad * 8];
            if (SPLIT) al[i] = *(const short8*)&AsL[cur * ASZ + (wm + i * 16 + l15) * BK + quad * 8];
        }
#pragma unroll
        for (int j = 0; j < FN; ++j) {
            bh[j] = *(const short8*)&BsH[cur * BSZ + (wn + j * 16 + l15) * BK + quad * 8];
            if (SPLIT) bl[j] = *(const short8*)&BsL[cur * BSZ + (wn + j * 16 + l15) * BK + quad * 8];
        }
#pragma unroll
        for (int i = 0; i < FM; ++i)
#pragma unroll
            for (int j = 0; j < FN; ++j) {
                acc[i][j] = __builtin_amdgcn_mfma_f32_16x16x32_bf16(ah[i], bh[j], acc[i][j], 0, 0, 0);
                if (SPLIT) {
                    acc[i][j] = __builtin_amdgcn_mfma_f32_16x16x32_bf16(ah[i], bl[j], acc[i][j], 0, 0, 0);
                    acc[i][j] = __builtin_amdgcn_mfma_f32_16x16x32_bf16(al[i], bh[j], acc[i][j], 0, 0, 0);
                }
            }

        __syncthreads();      // drains this iter's prefetch; next buf ready
    }

#pragma unroll
    for (int i = 0; i < FM; ++i)
#pragma unroll
        for (int j = 0; j < FN; ++j) {
            const int m = m0 + wm + i * 16 + quad * 4;
            const int n = n0 + wn + j * 16 + l15;
#pragma unroll
            for (int r = 0; r < 4; ++r) {
                const float v = acc[i][j][r];
                const long idx = (long)(m + r) * ldc + n;
                if (OUTMODE == 0) {
                    Cf[idx] = v;
                } else if (OUTMODE == 1 || OUTMODE == 3) {
                    Ch[idx] = f2bf(v);
                } else {
                    const unsigned short hi = f2bf(v);
                    Ch[idx] = hi;
                    Cl[idx] = f2bf(v - bf2f(hi));
                }
            }
        }

    if (OUTMODE == 3) {
        const int slot = (blockIdx.z * gridDim.x + blockIdx.x) * 2 + (wn >> 6);
#pragma unroll
        for (int i = 0; i < FM; ++i)
#pragma unroll
            for (int r = 0; r < 4; ++r) {
                float s = 0.f, q = 0.f;
#pragma unroll
                for (int j = 0; j < FN; ++j) {
                    const float v = acc[i][j][r];
                    s += v; q += v * v;
                }
#pragma unroll
                for (int msk = 1; msk < 16; msk <<= 1) {
                    s += __shfl_xor(s, msk, 64);
                    q += __shfl_xor(q, msk, 64);
                }
                if (l15 == 0) {
                    const int row = m0 + wm + i * 16 + quad * 4 + r;
                    S1[(long)row * 256 + slot] = s;
                    S2[(long)row * 256 + slot] = q;
                }
            }
    }
}

// ---------------- fused scores+softmax+y v5.1 (R4 body, kh=2) ----------------
// 512 blocks (b = id&7, kh = (id>>3)&1, qt = id>>4), 4 waves.
// S phase: 8 chunks of 32 c; chunk kc lives in column-half kc&1 of the
//   [128][64]+swz64 phi tile; per chunk {gload kc+2 | MFMA kc | write kc+1}
//   then ONE barrier. PV: square tiling (64q x 64p/wave), 4 chunks of 32 keys.
// LDS: FG 32,768B (aliased phi/G) + Pw 17,408B + Aly 256B = 50,432B.
#define PSTRP 136   // P LDS row stride (128 keys + 8 pad)

// swizzled short-offset into a [rows][64-short] tile: 16B slot ^= row&7
__device__ __forceinline__ int swz64(int row, int slot) {
    return (row << 6) + (((slot ^ row) & 7) << 3);
}

__global__ __launch_bounds__(256, 2) void fused_attn(
    const unsigned short* __restrict__ thphH,
    const unsigned short* __restrict__ thphL,
    const unsigned short* __restrict__ gbf,
    float* __restrict__ yp,       // [2][B][N][P] fp32 partials (self-normalized)
    float2* __restrict__ ml)      // [2][B*N] {m, l}
{
    const int N = 2048, P = 256, P2 = 512;
    const int id = blockIdx.x;
    const int b  = id & 7;            // XCD-locality heuristic
    const int kh = (id >> 3) & 1;     // key half
    const int qt = id >> 4;           // 0..31
    const int q0 = qt * 64;

    const unsigned short* thB = thphH + (long)b * N * P2;
    const unsigned short* tlB = thphL + (long)b * N * P2;
    const unsigned short* gB  = gbf   + (long)b * P * N;
    float*  ypB = yp + (long)kh * (8L * N * P) + (long)b * N * P;
    float2* mlB = ml + (long)kh * (8L * N) + (long)b * N;

    // phi hi/lo and G share the same LDS (disjoint phases / halves, fenced)
    __shared__ unsigned short FG[2 * 128 * 64];       // 16,384 shorts = 32,768 B
    unsigned short* Fh = FG;                          // [128][64] swizzled
    unsigned short* Fl = FG + 128 * 64;
    unsigned short* Gs = FG;                          // [256][64] swizzled
    __shared__ unsigned short Pw[4][16 * PSTRP];      // per-rowgroup P (shared)
    __shared__ float Aly[64];                         // per-row alpha / linv

    const int tid = threadIdx.x;
    const int wid = tid >> 6, lane = tid & 63;
    const int l15 = lane & 15, quad = lane >> 4;

    // theta fragments in registers: wave rows [q0+wid*16, +16), A m = l15
    short8 tHr[8], tLr[8];
    {
        const unsigned short* t1 = thB + (long)(q0 + wid * 16 + l15) * P2;
        const unsigned short* t2 = tlB + (long)(q0 + wid * 16 + l15) * P2;
#pragma unroll
        for (int kt = 0; kt < 8; ++kt) {
            tHr[kt] = *(const short8*)&t1[kt * 32 + quad * 8];
            tLr[kt] = *(const short8*)&t2[kt * 32 + quad * 8];
        }
    }

    float mrun[4], lrun[4];
#pragma unroll
    for (int r = 0; r < 4; ++r) { mrun[r] = -1e30f; lrun[r] = 0.f; }

    // oacc[g*4+pj]: rows g*16+quad*4+r, cols wid*64+pj*16+l15
    floatx4 oacc[16];
#pragma unroll
    for (int p = 0; p < 16; ++p) oacc[p] = (floatx4){0.f, 0.f, 0.f, 0.f};

    // staging: prow4 = tid>>2 (0..63), lslot = tid&3 (16B granule in 32-short half)
    const int prow4 = tid >> 2, lslot = tid & 3;
    short8 pfH[2][2], pfL[2][2];   // [set][s], set = chunk&1 (static under unroll)
    short8 pg[2][4];

    for (int mt = 0; mt < 8; ++mt) {
        const int m0 = kh * 1024 + mt * 128;

        // ---- S phase: 8 chunks of 32 c, half-column dbuf ----
        floatx4 sacc[8];
#pragma unroll
        for (int j = 0; j < 8; ++j) sacc[j] = (floatx4){0.f, 0.f, 0.f, 0.f};

        // prologue: chunk0 -> half0, prefetch chunk1.
#pragma unroll
        for (int s = 0; s < 2; ++s) {
            const long o = (long)(m0 + s * 64 + prow4) * P2 + P + 0 * 32 + lslot * 8;
            pfH[0][s] = *(const short8*)&thB[o];
            pfL[0][s] = *(const short8*)&tlB[o];
        }
#pragma unroll
        for (int s = 0; s < 2; ++s) {
            const int row = s * 64 + prow4;
            *(short8*)&Fh[swz64(row, lslot)] = pfH[0][s];
            *(short8*)&Fl[swz64(row, lslot)] = pfL[0][s];
        }
#pragma unroll
        for (int s = 0; s < 2; ++s) {
            const long o = (long)(m0 + s * 64 + prow4) * P2 + P + 1 * 32 + lslot * 8;
            pfH[1][s] = *(const short8*)&thB[o];
            pfL[1][s] = *(const short8*)&tlB[o];
        }
        __syncthreads();

#pragma unroll
        for (int kc = 0; kc < 8; ++kc) {
            if (kc < 6) {                        // prefetch chunk kc+2 into set kc&1
#pragma unroll
                for (int s = 0; s < 2; ++s) {
                    const long o = (long)(m0 + s * 64 + prow4) * P2 + P + (kc + 2) * 32 + lslot * 8;
                    pfH[kc & 1][s] = *(const short8*)&thB[o];
                    pfL[kc & 1][s] = *(const short8*)&tlB[o];
                }
            }
            const short8 aH = tHr[kc];
            const short8 aL = tLr[kc];
            const int half = (kc & 1) * 4;
            __builtin_amdgcn_s_setprio(1);
#pragma unroll
            for (int j = 0; j < 8; ++j) {
                const int ro = swz64(j * 16 + l15, half + quad);
                const short8 bh = *(const short8*)&Fh[ro];
                const short8 bl = *(const short8*)&Fl[ro];
                sacc[j] = __builtin_amdgcn_mfma_f32_16x16x32_bf16(aH, bh, sacc[j], 0, 0, 0);
                sacc[j] = __builtin_amdgcn_mfma_f32_16x16x32_bf16(aH, bl, sacc[j], 0, 0, 0);
                sacc[j] = __builtin_amdgcn_mfma_f32_16x16x32_bf16(aL, bh, sacc[j], 0, 0, 0);
            }
            __builtin_amdgcn_s_setprio(0);
            if (kc < 7) {                        // write chunk kc+1 into other half
                const int wh = ((kc + 1) & 1) * 4;
#pragma unroll
                for (int s = 0; s < 2; ++s) {
                    const int row = s * 64 + prow4;
                    *(short8*)&Fh[swz64(row, wh + lslot)] = pfH[(kc + 1) & 1][s];
                    *(short8*)&Fl[swz64(row, wh + lslot)] = pfL[(kc + 1) & 1][s];
                }
            }
            __syncthreads();
        }

        // ---- online softmax (registers only; rows = quad*4+r) ----
        float alpha[4];
#pragma unroll
        for (int r = 0; r < 4; ++r) {
            float v = sacc[0][r];
#pragma unroll
            for (int j = 1; j < 8; ++j) v = fmaxf(v, sacc[j][r]);
            v = fmaxf(v, __shfl_xor(v, 1, 64));
            v = fmaxf(v, __shfl_xor(v, 2, 64));
            v = fmaxf(v, __shfl_xor(v, 4, 64));
            v = fmaxf(v, __shfl_xor(v, 8, 64));
            const float mo = mrun[r];
            const float mn = fmaxf(mo, v);
            mrun[r] = mn;
            alpha[r] = __expf(mo - mn);
        }
        float lpart[4] = {0.f, 0.f, 0.f, 0.f};
#pragma unroll
        for (int j = 0; j < 8; ++j)
#pragma unroll
            for (int r = 0; r < 4; ++r) {
                const float p = __expf(sacc[j][r] - mrun[r]);
                Pw[wid][(quad * 4 + r) * PSTRP + j * 16 + l15] = f2bf(p);
                lpart[r] += p;
            }
#pragma unroll
        for (int r = 0; r < 4; ++r) {
            float s = lpart[r];
            s += __shfl_xor(s, 1, 64);
            s += __shfl_xor(s, 2, 64);
            s += __shfl_xor(s, 4, 64);
            s += __shfl_xor(s, 8, 64);
            lrun[r] = lrun[r] * alpha[r] + s;
        }
        if (l15 == 0) {                    // publish row alphas for PV rescale
#pragma unroll
            for (int r = 0; r < 4; ++r) Aly[wid * 16 + quad * 4 + r] = alpha[r];
        }

        // ---- PV phase: square tiling, 4 chunks of 32 keys, half dbuf ----
#pragma unroll
        for (int s = 0; s < 4; ++s)
            pg[0][s] = *(const short8*)&gB[(long)(s * 64 + prow4) * N + m0 + 0 * 32 + lslot * 8];
#pragma unroll
        for (int s = 0; s < 4; ++s)
            *(short8*)&Gs[swz64(s * 64 + prow4, lslot)] = pg[0][s];
#pragma unroll
        for (int s = 0; s < 4; ++s)
            pg[1][s] = *(const short8*)&gB[(long)(s * 64 + prow4) * N + m0 + 1 * 32 + lslot * 8];
        __syncthreads();   // G0 + Pw + Aly visible

        float alr[4][4];
#pragma unroll
        for (int g = 0; g < 4; ++g)
#pragma unroll
            for (int r = 0; r < 4; ++r) alr[g][r] = Aly[g * 16 + quad * 4 + r];
        int noresc = 1;
#pragma unroll
        for (int g = 0; g < 4; ++g)
#pragma unroll
            for (int r = 0; r < 4; ++r) noresc &= (alr[g][r] == 1.f);
        if (!__all(noresc)) {
#pragma unroll
            for (int g = 0; g < 4; ++g)
#pragma unroll
                for (int pj = 0; pj < 4; ++pj)
#pragma unroll
                    for (int r = 0; r < 4; ++r) oacc[g * 4 + pj][r] *= alr[g][r];
        }

#pragma unroll
        for (int mc = 0; mc < 4; ++mc) {
            if (mc < 2) {                        // prefetch chunk mc+2 into set mc&1
#pragma unroll
                for (int s = 0; s < 4; ++s)
                    pg[mc & 1][s] = *(const short8*)&gB[(long)(s * 64 + prow4) * N + m0 + (mc + 2) * 32 + lslot * 8];
            }
            const int half = (mc & 1) * 4;
            short8 af[4];
#pragma unroll
            for (int g = 0; g < 4; ++g)
                af[g] = *(const short8*)&Pw[g][l15 * PSTRP + mc * 32 + quad * 8];
            __builtin_amdgcn_s_setprio(1);
#pragma unroll
            for (int pj = 0; pj < 4; ++pj) {
                const short8 bg = *(const short8*)&Gs[swz64(wid * 64 + pj * 16 + l15, half + quad)];
#pragma unroll
                for (int g = 0; g < 4; ++g)
                    oacc[g * 4 + pj] = __builtin_amdgcn_mfma_f32_16x16x32_bf16(af[g], bg, oacc[g * 4 + pj], 0, 0, 0);
            }
            __builtin_amdgcn_s_setprio(0);
            if (mc < 3) {                        // write chunk mc+1 into other half
                const int wh = ((mc + 1) & 1) * 4;
#pragma unroll
                for (int s = 0; s < 4; ++s)
                    *(short8*)&Gs[swz64(s * 64 + prow4, wh + lslot)] = pg[(mc + 1) & 1][s];
                __syncthreads();
            }
        }
    }

    // ---- finalize: publish 1/l, scale, write fp32 partial + (m,l) ----
    if (l15 == 0) {
#pragma unroll
        for (int r = 0; r < 4; ++r) Aly[wid * 16 + quad * 4 + r] = 1.0f / lrun[r];
    }
    __syncthreads();
    float liv[4][4];
#pragma unroll
    for (int g = 0; g < 4; ++g)
#pragma unroll
        for (int r = 0; r < 4; ++r) liv[g][r] = Aly[g * 16 + quad * 4 + r];
#pragma unroll
    for (int g = 0; g < 4; ++g)
#pragma unroll
        for (int pj = 0; pj < 4; ++pj)
#pragma unroll
            for (int r = 0; r < 4; ++r) {
                const int row = q0 + g * 16 + quad * 4 + r;
                const int col = wid * 64 + pj * 16 + l15;
                ypB[(long)row * P + col] = oacc[g * 4 + pj][r] * liv[g][r];
            }
    if (l15 == 0) {
#pragma unroll
        for (int r = 0; r < 4; ++r) {
            const int row = q0 + wid * 16 + quad * 4 + r;
            mlB[row] = float2{mrun[r], lrun[r]};
        }
    }
}

// merge the two key-half partials: y = f1*y1 + f2*y2, f_i = l_i e^{m_i-m}/Z
__global__ __launch_bounds__(256) void attn_merge(
    const float* __restrict__ yp, const float2* __restrict__ ml,
    unsigned short* __restrict__ ybf)
{
    const long HALF = 8L * 2048 * 256;
    const long t = (long)blockIdx.x * 256 + threadIdx.x;
    const long row = t >> 5;
    const int  c0  = ((int)t & 31) * 8;
    const float2 a = ml[row];
    const float2 c = ml[8L * 2048 + row];
    const float mx = fmaxf(a.x, c.x);
    const float w1 = a.y * __expf(a.x - mx);
    const float w2 = c.y * __expf(c.x - mx);
    const float inv = 1.0f / (w1 + w2);
    const float f1 = w1 * inv, f2 = w2 * inv;
    const long base = row * 256 + c0;
    const float4 u0 = *(const float4*)&yp[base];
    const float4 u1 = *(const float4*)&yp[base + 4];
    const float4 v0 = *(const float4*)&yp[HALF + base];
    const float4 v1 = *(const float4*)&yp[HALF + base + 4];
    ushort4 o0, o1;
    o0.x = f2bf(f1 * u0.x + f2 * v0.x);
    o0.y = f2bf(f1 * u0.y + f2 * v0.y);
    o0.z = f2bf(f1 * u0.z + f2 * v0.z);
    o0.w = f2bf(f1 * u0.w + f2 * v0.w);
    o1.x = f2bf(f1 * u1.x + f2 * v1.x);
    o1.y = f2bf(f1 * u1.y + f2 * v1.y);
    o1.z = f2bf(f1 * u1.z + f2 * v1.z);
    o1.w = f2bf(f1 * u1.w + f2 * v1.w);
    *(ushort4*)&ybf[base] = o0;
    *(ushort4*)&ybf[base + 4] = o1;
}

// ---------------- BN finalize + apply ----------------
__global__ __launch_bounds__(256) void bn_finalize(
    const float* __restrict__ p1, const float* __restrict__ p2,
    float* __restrict__ mean, float* __restrict__ rstd, float cnt)
{
    const int c = blockIdx.x, t = threadIdx.x;
    __shared__ float rs[256], rq[256];
    rs[t] = p1[(long)c * 256 + t];
    rq[t] = p2[(long)c * 256 + t];
    __syncthreads();
    for (int st = 128; st > 0; st >>= 1) {
        if (t < st) { rs[t] += rs[t + st]; rq[t] += rq[t + st]; }
        __syncthreads();
    }
    if (t == 0) {
        const float m = rs[0] / cnt;
        mean[c] = m;
        rstd[c] = rsqrtf(rq[0] / cnt - m * m + 1e-5f);
    }
}

__global__ __launch_bounds__(256) void bn_apply_bf(
    const unsigned short* __restrict__ z, const float* __restrict__ x,
    const float* __restrict__ mean, const float* __restrict__ rstd,
    const float* __restrict__ gamma, const float* __restrict__ beta,
    float* __restrict__ out, int C, int N)
{
    const long i = ((long)blockIdx.x * 256 + threadIdx.x) * 8;
    const int c = (int)((i / N) % C);
    const float mu = mean[c], rs = rstd[c], ga = gamma[c], be = beta[c];
    const ushort4 z0 = *(const ushort4*)&z[i];
    const ushort4 z1 = *(const ushort4*)&z[i + 4];
    const float4 x0 = *(const float4*)&x[i];
    const float4 x1 = *(const float4*)&x[i + 4];
    float4 o0, o1;
    o0.x = (bf2f(z0.x) - mu) * rs * ga + be + x0.x;
    o0.y = (bf2f(z0.y) - mu) * rs * ga + be + x0.y;
    o0.z = (bf2f(z0.z) - mu) * rs * ga + be + x0.z;
    o0.w = (bf2f(z0.w) - mu) * rs * ga + be + x0.w;
    o1.x = (bf2f(z1.x) - mu) * rs * ga + be + x1.x;
    o1.y = (bf2f(z1.y) - mu) * rs * ga + be + x1.y;
    o1.z = (bf2f(z1.z) - mu) * rs * ga + be + x1.z;
    o1.w = (bf2f(z1.w) - mu) * rs * ga + be + x1.w;
    *(float4*)&out[i] = o0;
    *(float4*)&out[i + 4] = o1;
}

extern "C" void kernel_launch(void* const* d_in, const int* in_sizes, int n_in,
                              void* d_out, int out_size, void* d_ws, size_t ws_size,
                              hipStream_t stream)
{
    const int B = 8, C = 512, N = 2048, P = 256;
    const float* x      = (const float*)d_in[0];
    const float* Wg     = (const float*)d_in[1];
    const float* Wtheta = (const float*)d_in[2];
    const float* Wphi   = (const float*)d_in[3];
    const float* Wz     = (const float*)d_in[4];
    const float* gamma  = (const float*)d_in[5];
    const float* beta   = (const float*)d_in[6];
    float* out = (float*)d_out;

    // ---- workspace layout (float units), same as round 9 ----
    float* ws = (float*)d_ws;
    const long NCle = (long)N * C;            // 1,048,576 per batch (= N*2P)
    const long NP   = (long)N * P;            // 524,288 per batch
    const long R0   = (long)B * NCle;         // 8.39M floats
    unsigned short* xtH   = (unsigned short*)ws;                // B*N*C
    unsigned short* xtL   = xtH + B * NCle;
    unsigned short* zbf   = (unsigned short*)ws;                // aliases xt (dead)
    unsigned short* thphH = (unsigned short*)(ws + R0);         // B*N*2P
    unsigned short* thphL = thphH + B * NCle;                   // B*N*2P
    unsigned short* gbf   = (unsigned short*)(ws + 2 * R0);     // B*P*N
    unsigned short* fbf   = gbf + B * NP;                       // attn partial region
    unsigned short* ybf   = fbf + (long)B * N * N;              // B*N*P
    unsigned short* W2H   = ybf + B * NP;                       // 2P*C
    unsigned short* W2L   = W2H + 2L * P * C;
    unsigned short* WgB   = W2L + 2L * P * C;                   // P*C
    unsigned short* WzB   = WgB + (long)P * C;
    // attn split-K partials in the dead fbf region; ml in dead xtL region.
    float*          yp    = (float*)fbf;                        // [2][B][N][P] fp32
    float2*         ml    = (float2*)(ws + 6L * 1024 * 1024);   // [2][B*N], in xtL
    // BN scratch aliases thph region (dead after fused_attn): [C][256] x2
    float*          bnp1  = ws + R0;
    float*          bnp2  = bnp1 + (long)C * 256;
    float*          mean  = bnp2 + (long)C * 256;
    float*          rstd  = mean + C;

    const long sX = (long)C * N;
    const int  P2 = 2 * P;

    // 1: transpose+split x -> xT hi/lo [B][N][C]
    transpose_split<<<dim3(N / 32, C / 32, B), 256, 0, stream>>>(x, xtH, xtL, C, N);
    // 2: weight preps
    split_w2<<<(2 * P * C + 255) / 256, 256, 0, stream>>>(Wtheta, Wphi, W2H, W2L, P * C);
    cast_bf16<<<P * C / 1024, 256, 0, stream>>>(Wg, WgB);
    cast_bf16<<<P * C / 1024, 256, 0, stream>>>(Wz, WzB);

    // 3: thph [B][N][2P] = xT @ W2^T (split in/out); 128x128, 512 blocks
    mfma_gemm<true, 2, 4, 4><<<dim3(P2 / 128, N / 128, B), 256, 0, stream>>>(
        xtH, xtL, W2H, W2L, thphH, thphL, C, C, C, P2, NCle, 0, NCle, nullptr, nullptr);
    // 4: g [B][P][N] = Wg @ xT^T (plain, bf16 out); 64x128, 512 blocks
    mfma_gemm<false, 1, 2, 4><<<dim3(N / 128, P / 64, B), 256, 0, stream>>>(
        WgB, WgB, xtH, xtH, gbf, gbf, C, C, C, N, 0, NCle, NP, nullptr, nullptr);

    // 5: fused scores+softmax+y, split-K x2 over keys (512 blocks, 2/CU) + merge
    fused_attn<<<dim3(512), 256, 0, stream>>>(thphH, thphL, gbf, yp, ml);
    attn_merge<<<dim3(2048), 256, 0, stream>>>(yp, ml, ybf);

    // 6: z [B][C][N] bf16 = Wz @ yT^T, BN partials (thph dead now)
    mfma_gemm<false, 3, 4, 4><<<dim3(N / 128, C / 128, B), 256, 0, stream>>>(
        WzB, WzB, ybf, ybf, zbf, zbf, P, P, P, N, 0, NP, sX, bnp1, bnp2);

    // 7: BN finalize + apply + residual
    bn_finalize<<<C, 256, 0, stream>>>(bnp1, bnp2, mean, rstd, (float)B * N);
    bn_apply_bf<<<(int)((B * sX) / 2048), 256, 0, stream>>>(zbf, x, mean, rstd, gamma, beta, out, C, N);
}